// Round 6
// baseline (418.887 us; speedup 1.0000x reference)
//
#include <hip/hip_runtime.h>
#include <math.h>

#define NN 16384
#define EE 262144
#define FF 32
#define HH 128
#define BB 16
#define DI 256
#define DS 16
#define DC 4
#define DTR 8
#define OUTW 1552
#define NCH 512
#define CHLEN 32    // NCH*CHLEN == NN

// ---------------------------------------------------------------- utilities
__device__ __forceinline__ float siluf(float v) { return v / (1.f + __expf(-v)); }
__device__ __forceinline__ float softplusf(float v) {
    return fmaxf(v, 0.f) + __logf(1.f + __expf(-fabsf(v)));
}

// ---------------------------------------------------------------- zero scratch (replaces 3 memsets)
__global__ void zero_kernel(int* __restrict__ cnt, float* __restrict__ ge,
                            int* __restrict__ counts) {
    int idx = blockIdx.x * blockDim.x + threadIdx.x;
    if (idx < NN) cnt[idx] = 0;
    if (idx < BB * HH) ge[idx] = 0.f;
    if (idx < BB) counts[idx] = 0;
}

// ---------------------------------------------------------------- CSR build
__global__ void deg_kernel(const int* __restrict__ dst, int* __restrict__ cnt) {
    int e = blockIdx.x * blockDim.x + threadIdx.x;
    if (e < EE) atomicAdd(&cnt[dst[e]], 1);
}

__global__ __launch_bounds__(1024) void prefix_kernel(const int* __restrict__ cnt,
                                                      int* __restrict__ rowptr,
                                                      int* __restrict__ cursor,
                                                      float* __restrict__ dinv) {
    __shared__ int part[1024];
    int tid = threadIdx.x;
    int4 c4[4];
#pragma unroll
    for (int j = 0; j < 4; j++) c4[j] = ((const int4*)cnt)[tid * 4 + j];
    int v[16] = {c4[0].x, c4[0].y, c4[0].z, c4[0].w, c4[1].x, c4[1].y, c4[1].z, c4[1].w,
                 c4[2].x, c4[2].y, c4[2].z, c4[2].w, c4[3].x, c4[3].y, c4[3].z, c4[3].w};
    int s = 0;
#pragma unroll
    for (int j = 0; j < 16; j++) s += v[j];
    part[tid] = s;
    __syncthreads();
    for (int off = 1; off < 1024; off <<= 1) {
        int t = (tid >= off) ? part[tid - off] : 0;
        __syncthreads();
        part[tid] += t;
        __syncthreads();
    }
    int running = part[tid] - s;
    int rp[16];
    float dv[16];
#pragma unroll
    for (int j = 0; j < 16; j++) {
        rp[j] = running;
        running += v[j];
        dv[j] = rsqrtf((float)(v[j] + 1));  // +1 self loop
    }
#pragma unroll
    for (int j = 0; j < 4; j++) {
        int4 r4; r4.x = rp[j*4]; r4.y = rp[j*4+1]; r4.z = rp[j*4+2]; r4.w = rp[j*4+3];
        ((int4*)rowptr)[tid * 4 + j] = r4;
        ((int4*)cursor)[tid * 4 + j] = r4;
        float4 d4; d4.x = dv[j*4]; d4.y = dv[j*4+1]; d4.z = dv[j*4+2]; d4.w = dv[j*4+3];
        ((float4*)dinv)[tid * 4 + j] = d4;
    }
    if (tid == 1023) rowptr[NN] = part[1023];
}

__global__ void scatter_kernel(const int* __restrict__ src, const int* __restrict__ dst,
                               int* __restrict__ cursor, int* __restrict__ col) {
    int e = blockIdx.x * blockDim.x + threadIdx.x;
    if (e < EE) {
        int d = dst[e];
        int pos = atomicAdd(&cursor[d], 1);
        col[pos] = src[e];
    }
}

// ---------------------------------------------------------------- GEMM (fp32, 64x64 tile)
__global__ __launch_bounds__(256) void gemm_k(const float* __restrict__ A,
                                              const float* __restrict__ B,
                                              const float* __restrict__ bias,
                                              float* __restrict__ C,
                                              int M, int Nn, int K, int act) {
    __shared__ float As[16][68];
    __shared__ float Bs[16][68];
    int tid = threadIdx.x;
    int m0 = blockIdx.y * 64;
    int n0 = blockIdx.x * 64;
    int ty = tid >> 4, tx = tid & 15;
    float acc[4][4] = {{0.f}};
    for (int k0 = 0; k0 < K; k0 += 16) {
#pragma unroll
        for (int l = 0; l < 4; l++) {
            int idx = tid + l * 256;
            int i = idx >> 4, j = idx & 15;
            As[j][i] = A[(size_t)(m0 + i) * K + k0 + j];
        }
#pragma unroll
        for (int l = 0; l < 4; l++) {
            int idx = tid + l * 256;
            int i = idx >> 6, j = idx & 63;
            int n = n0 + j;
            Bs[i][j] = (n < Nn) ? B[(size_t)(k0 + i) * Nn + n] : 0.f;
        }
        __syncthreads();
#pragma unroll
        for (int kk = 0; kk < 16; kk++) {
            float4 a4 = *(const float4*)&As[kk][ty * 4];
            float4 b4 = *(const float4*)&Bs[kk][tx * 4];
            float av[4] = {a4.x, a4.y, a4.z, a4.w};
            float bv[4] = {b4.x, b4.y, b4.z, b4.w};
#pragma unroll
            for (int r = 0; r < 4; r++)
#pragma unroll
                for (int c = 0; c < 4; c++) acc[r][c] = fmaf(av[r], bv[c], acc[r][c]);
        }
        __syncthreads();
    }
    int nb = n0 + tx * 4;
    if (nb < Nn) {
        float4 bi4 = {0.f, 0.f, 0.f, 0.f};
        if (bias) bi4 = *(const float4*)&bias[nb];
#pragma unroll
        for (int r = 0; r < 4; r++) {
            int m = m0 + ty * 4 + r;
            float4 v;
            v.x = acc[r][0] + bi4.x; v.y = acc[r][1] + bi4.y;
            v.z = acc[r][2] + bi4.z; v.w = acc[r][3] + bi4.w;
            if (act == 1) {
                v.x = fmaxf(v.x, 0.f); v.y = fmaxf(v.y, 0.f);
                v.z = fmaxf(v.z, 0.f); v.w = fmaxf(v.w, 0.f);
            }
            *(float4*)&C[(size_t)m * Nn + nb] = v;
        }
    }
}

// ---------------------------------------------------------------- fused relu(nf@W_in+b) @ W_g1
union SMemIn {
    struct { float Ns[64][33]; float Ws[32][132]; } s1;   // step-1 staging
    float Bs[16][68];                                     // step-2 W_g1 chunk
};

__global__ __launch_bounds__(256) void gemm_in_g1(const float* __restrict__ nf,
                                                  const float* __restrict__ W_in,
                                                  const float* __restrict__ b_in,
                                                  const float* __restrict__ W_g1,
                                                  float* __restrict__ out) {
    __shared__ SMemIn sm;
    __shared__ float Hs[128][68];   // h^T: Hs[k][m]
    int tid = threadIdx.x;
    int m0 = blockIdx.y * 64;
    int n0 = blockIdx.x * 64;
    int ty = tid >> 4, tx = tid & 15;
#pragma unroll
    for (int l = 0; l < 2; l++) {
        int q = tid + l * 256;
        int r = q >> 3, c4 = (q & 7) * 4;
        *(float4*)&sm.s1.Ns[r][c4] = *(const float4*)&nf[(size_t)(m0 + r) * FF + c4];
    }
#pragma unroll
    for (int l = 0; l < 4; l++) {
        int q = tid + l * 256;
        int r = q >> 5, c4 = (q & 31) * 4;
        *(float4*)&sm.s1.Ws[r][c4] = *(const float4*)&W_in[(size_t)r * HH + c4];
    }
    __syncthreads();
    {
        float4 b0 = *(const float4*)&b_in[tx * 4];
        float4 b1 = *(const float4*)&b_in[64 + tx * 4];
        float hacc[4][8];
#pragma unroll
        for (int r = 0; r < 4; r++) {
            hacc[r][0] = b0.x; hacc[r][1] = b0.y; hacc[r][2] = b0.z; hacc[r][3] = b0.w;
            hacc[r][4] = b1.x; hacc[r][5] = b1.y; hacc[r][6] = b1.z; hacc[r][7] = b1.w;
        }
#pragma unroll
        for (int k = 0; k < FF; k++) {
            float av[4];
#pragma unroll
            for (int r = 0; r < 4; r++) av[r] = sm.s1.Ns[ty * 4 + r][k];
            float wv[8];
#pragma unroll
            for (int c = 0; c < 4; c++) {
                wv[c]     = sm.s1.Ws[k][tx * 4 + c];
                wv[c + 4] = sm.s1.Ws[k][64 + tx * 4 + c];
            }
#pragma unroll
            for (int r = 0; r < 4; r++)
#pragma unroll
                for (int c = 0; c < 8; c++) hacc[r][c] = fmaf(av[r], wv[c], hacc[r][c]);
        }
#pragma unroll
        for (int r = 0; r < 4; r++)
#pragma unroll
            for (int c = 0; c < 4; c++) {
                Hs[tx * 4 + c][ty * 4 + r]      = fmaxf(hacc[r][c], 0.f);
                Hs[64 + tx * 4 + c][ty * 4 + r] = fmaxf(hacc[r][c + 4], 0.f);
            }
    }
    __syncthreads();
    float acc[4][4] = {{0.f}};
    for (int k0 = 0; k0 < HH; k0 += 16) {
        *(float4*)&sm.Bs[tid >> 4][(tid & 15) * 4] =
            *(const float4*)&W_g1[(size_t)(k0 + (tid >> 4)) * HH + n0 + (tid & 15) * 4];
        __syncthreads();
#pragma unroll
        for (int kk = 0; kk < 16; kk++) {
            float4 a4 = *(const float4*)&Hs[k0 + kk][ty * 4];
            float4 b4 = *(const float4*)&sm.Bs[kk][tx * 4];
            float av[4] = {a4.x, a4.y, a4.z, a4.w};
            float bv[4] = {b4.x, b4.y, b4.z, b4.w};
#pragma unroll
            for (int r = 0; r < 4; r++)
#pragma unroll
                for (int c = 0; c < 4; c++) acc[r][c] = fmaf(av[r], bv[c], acc[r][c]);
        }
        __syncthreads();
    }
#pragma unroll
    for (int r = 0; r < 4; r++) {
        int m = m0 + ty * 4 + r;
        float4 v;
        v.x = acc[r][0]; v.y = acc[r][1]; v.z = acc[r][2]; v.w = acc[r][3];
        *(float4*)&out[(size_t)m * HH + n0 + tx * 4] = v;
    }
}

// ---------------------------------------------------------------- big-tile GEMM, 512 threads, TRANSPOSED output
__global__ __launch_bounds__(512, 4) void gemm_big512_t(const float* __restrict__ A,
                                                        const float* __restrict__ B,
                                                        float* __restrict__ CT,
                                                        int M, int Nn, int K) {
    __shared__ float As[16][132];
    __shared__ float Bs[16][132];
    int tid = threadIdx.x;
    int m0 = blockIdx.y * 128;
    int n0 = blockIdx.x * 128;
    int ty = tid >> 4;          // 0..31 -> m rows ty*4..ty*4+3
    int tx = tid & 15;          // n cols tx*4 and 64+tx*4
    float acc[4][8] = {{0.f}};
    for (int k0 = 0; k0 < K; k0 += 16) {
        {   // A: 128 m x 16 k, one float4 per thread -> As[k][m]
            int m = tid >> 2;
            int kc = (tid & 3) * 4;
            float4 a = *(const float4*)&A[(size_t)(m0 + m) * K + k0 + kc];
            As[kc + 0][m] = a.x; As[kc + 1][m] = a.y;
            As[kc + 2][m] = a.z; As[kc + 3][m] = a.w;
        }
        {   // B: 16 k x 128 n, one float4 per thread
            int krow = tid >> 5;
            int c4 = (tid & 31) * 4;
            *(float4*)&Bs[krow][c4] = *(const float4*)&B[(size_t)(k0 + krow) * Nn + n0 + c4];
        }
        __syncthreads();
#pragma unroll
        for (int kk = 0; kk < 16; kk++) {
            float4 a4 = *(const float4*)&As[kk][ty * 4];
            float4 b0 = *(const float4*)&Bs[kk][tx * 4];
            float4 b1 = *(const float4*)&Bs[kk][64 + tx * 4];
            float av[4] = {a4.x, a4.y, a4.z, a4.w};
            float bv[8] = {b0.x, b0.y, b0.z, b0.w, b1.x, b1.y, b1.z, b1.w};
#pragma unroll
            for (int r = 0; r < 4; r++)
#pragma unroll
                for (int c = 0; c < 8; c++) acc[r][c] = fmaf(av[r], bv[c], acc[r][c]);
        }
        __syncthreads();
    }
    // transposed store: CT[n][m]
#pragma unroll
    for (int cc = 0; cc < 4; cc++) {
        float4 v;
        v.x = acc[0][cc]; v.y = acc[1][cc]; v.z = acc[2][cc]; v.w = acc[3][cc];
        *(float4*)&CT[(size_t)(n0 + tx * 4 + cc) * NN + m0 + ty * 4] = v;
        float4 u;
        u.x = acc[0][cc + 4]; u.y = acc[1][cc + 4]; u.z = acc[2][cc + 4]; u.w = acc[3][cc + 4];
        *(float4*)&CT[(size_t)(n0 + 64 + tx * 4 + cc) * NN + m0 + ty * 4] = u;
    }
}

// ---------------------------------------------------------------- xproj GEMM fused with conv+silu
__global__ __launch_bounds__(256) void gemm_xz_dblt(const float* __restrict__ xzt,
                                                    const float* __restrict__ B,
                                                    const float* __restrict__ cw,
                                                    const float* __restrict__ cb,
                                                    float* __restrict__ xst,
                                                    float* __restrict__ dblt) {
    __shared__ float As[16][68];
    __shared__ float Bs[16][68];
    __shared__ float Raw[16][72];   // raw xz: Raw[kk][q] = xz[k0+kk][m0-4+q], q in [0,68)
    __shared__ float Ct[64][41];
    int tid = threadIdx.x;
    int m0 = blockIdx.x * 64;
    int ty = tid >> 4, tx = tid & 15;
    float acc[4][4] = {{0.f}};
    for (int k0 = 0; k0 < DI; k0 += 16) {
#pragma unroll
        for (int l = 0; l < 2; l++) {
            int idx = tid + l * 256;
            if (idx < 272) {
                int kk = idx / 17, j = idx % 17;
                int tcol = m0 - 4 + j * 4;
                float4 v;
                if (tcol >= 0) v = *(const float4*)&xzt[(size_t)(k0 + kk) * NN + tcol];
                else { v.x = 0.f; v.y = 0.f; v.z = 0.f; v.w = 0.f; }
                *(float4*)&Raw[kk][j * 4] = v;
            }
        }
#pragma unroll
        for (int l = 0; l < 4; l++) {
            int idx = tid + l * 256;
            int i2 = idx >> 6, j2 = idx & 63;
            Bs[i2][j2] = (j2 < 40) ? B[(size_t)(k0 + i2) * 40 + j2] : 0.f;
        }
        __syncthreads();
#pragma unroll
        for (int l = 0; l < 4; l++) {
            int kk = (tid >> 6) + l * 4;
            int i = tid & 63;
            int d = k0 + kk;
            float w0 = cw[d * DC + 0], w1 = cw[d * DC + 1];
            float w2 = cw[d * DC + 2], w3 = cw[d * DC + 3];
            float v = siluf(cb[d] + w0 * Raw[kk][i + 1] + w1 * Raw[kk][i + 2]
                                  + w2 * Raw[kk][i + 3] + w3 * Raw[kk][i + 4]);
            As[kk][i] = v;
            xst[(size_t)d * NN + m0 + i] = v;
        }
        __syncthreads();
#pragma unroll
        for (int kk = 0; kk < 16; kk++) {
            float4 a4 = *(const float4*)&As[kk][ty * 4];
            float4 b4 = *(const float4*)&Bs[kk][tx * 4];
            float av[4] = {a4.x, a4.y, a4.z, a4.w};
            float bv[4] = {b4.x, b4.y, b4.z, b4.w};
#pragma unroll
            for (int r = 0; r < 4; r++)
#pragma unroll
                for (int c = 0; c < 4; c++) acc[r][c] = fmaf(av[r], bv[c], acc[r][c]);
        }
        __syncthreads();
    }
    if (tx * 4 < 40) {
#pragma unroll
        for (int r = 0; r < 4; r++) {
            int m = ty * 4 + r;
            Ct[m][tx * 4 + 0] = acc[r][0];
            Ct[m][tx * 4 + 1] = acc[r][1];
            Ct[m][tx * 4 + 2] = acc[r][2];
            Ct[m][tx * 4 + 3] = acc[r][3];
        }
    }
    __syncthreads();
#pragma unroll
    for (int l = 0; l < 10; l++) {
        int idx = tid + l * 256;
        int n = idx >> 6, m = idx & 63;
        dblt[(size_t)n * NN + m0 + m] = Ct[m][n];
    }
}

// ---------------------------------------------------------------- fused W_out GEMM + add + LayerNorm + POOL
__global__ __launch_bounds__(256) void gemm_at_ln_pool(const float* __restrict__ AT,
                                                       const float* __restrict__ B,
                                                       const float* __restrict__ hg,
                                                       const float* __restrict__ gamma,
                                                       const float* __restrict__ beta,
                                                       const int* __restrict__ batch,
                                                       float* __restrict__ ge,
                                                       int* __restrict__ counts) {
    __shared__ float As[16][36];
    __shared__ float Bs[16][132];
    __shared__ float lnb[32][132];
    __shared__ int gb[32];
    int tid = threadIdx.x;
    int m0 = blockIdx.x * 32;
    int ty = tid >> 4, tx = tid & 15;
    float acc[2][8] = {{0.f}};
    for (int k0 = 0; k0 < 256; k0 += 16) {
        {
            int idx = tid * 2;
            int kk = idx >> 5, i = idx & 31;
            As[kk][i] = AT[(size_t)(k0 + kk) * NN + m0 + i];
            As[kk][i + 1] = AT[(size_t)(k0 + kk) * NN + m0 + i + 1];
        }
        {
            int krow = tid >> 4;
            int c8 = (tid & 15) * 8;
            const float* bp = &B[(size_t)(k0 + krow) * HH + c8];
            *(float4*)&Bs[krow][c8] = *(const float4*)bp;
            *(float4*)&Bs[krow][c8 + 4] = *(const float4*)(bp + 4);
        }
        __syncthreads();
#pragma unroll
        for (int kk = 0; kk < 16; kk++) {
            float a0 = As[kk][ty * 2];
            float a1 = As[kk][ty * 2 + 1];
            float4 b0 = *(const float4*)&Bs[kk][tx * 4];
            float4 b1 = *(const float4*)&Bs[kk][64 + tx * 4];
            float bv[8] = {b0.x, b0.y, b0.z, b0.w, b1.x, b1.y, b1.z, b1.w};
#pragma unroll
            for (int c = 0; c < 8; c++) {
                acc[0][c] = fmaf(a0, bv[c], acc[0][c]);
                acc[1][c] = fmaf(a1, bv[c], acc[1][c]);
            }
        }
        __syncthreads();
    }
    if (tid < 32) gb[tid] = batch[m0 + tid];
    float4 g0 = *(const float4*)&gamma[tx * 4];
    float4 g1 = *(const float4*)&gamma[64 + tx * 4];
    float4 be0 = *(const float4*)&beta[tx * 4];
    float4 be1 = *(const float4*)&beta[64 + tx * 4];
    float gv[8] = {g0.x, g0.y, g0.z, g0.w, g1.x, g1.y, g1.z, g1.w};
    float bv[8] = {be0.x, be0.y, be0.z, be0.w, be1.x, be1.y, be1.z, be1.w};
#pragma unroll
    for (int r = 0; r < 2; r++) {
        int m = m0 + ty * 2 + r;
        float4 h0 = *(const float4*)&hg[(size_t)m * HH + tx * 4];
        float4 h1 = *(const float4*)&hg[(size_t)m * HH + 64 + tx * 4];
        float v[8] = {acc[r][0] + h0.x, acc[r][1] + h0.y, acc[r][2] + h0.z, acc[r][3] + h0.w,
                      acc[r][4] + h1.x, acc[r][5] + h1.y, acc[r][6] + h1.z, acc[r][7] + h1.w};
        float sum = 0.f;
#pragma unroll
        for (int c = 0; c < 8; c++) sum += v[c];
        sum += __shfl_xor(sum, 1); sum += __shfl_xor(sum, 2);
        sum += __shfl_xor(sum, 4); sum += __shfl_xor(sum, 8);
        float mu = sum * (1.f / 128.f);
        float vs = 0.f;
#pragma unroll
        for (int c = 0; c < 8; c++) { float dd = v[c] - mu; vs += dd * dd; }
        vs += __shfl_xor(vs, 1); vs += __shfl_xor(vs, 2);
        vs += __shfl_xor(vs, 4); vs += __shfl_xor(vs, 8);
        float inv = rsqrtf(vs * (1.f / 128.f) + 1e-5f);
        int lr = ty * 2 + r;
        float4 o0, o1;
        o0.x = (v[0] - mu) * inv * gv[0] + bv[0];
        o0.y = (v[1] - mu) * inv * gv[1] + bv[1];
        o0.z = (v[2] - mu) * inv * gv[2] + bv[2];
        o0.w = (v[3] - mu) * inv * gv[3] + bv[3];
        o1.x = (v[4] - mu) * inv * gv[4] + bv[4];
        o1.y = (v[5] - mu) * inv * gv[5] + bv[5];
        o1.z = (v[6] - mu) * inv * gv[6] + bv[6];
        o1.w = (v[7] - mu) * inv * gv[7] + bv[7];
        *(float4*)&lnb[lr][tx * 4] = o0;
        *(float4*)&lnb[lr][64 + tx * 4] = o1;
    }
    __syncthreads();
    if (tid < HH) {
        int f = tid;
        int gcur = gb[0];
        float acc2 = 0.f;
        int cnt = 0;
#pragma unroll 4
        for (int i = 0; i < 32; i++) {
            int g = gb[i];
            if (g != gcur) {
                atomicAdd(&ge[gcur * HH + f], acc2);
                if (f == 0) atomicAdd(&counts[gcur], cnt);
                acc2 = 0.f; cnt = 0; gcur = g;
            }
            acc2 += lnb[i][f];
            cnt++;
        }
        atomicAdd(&ge[gcur * HH + f], acc2);
        if (f == 0) atomicAdd(&counts[gcur], cnt);
    }
}

// ---------------------------------------------------------------- GCN gather, float4, 4-edge unroll
__global__ __launch_bounds__(256) void gcn_gather4(const float* __restrict__ xw,
                                                   const int* __restrict__ rowptr,
                                                   const int* __restrict__ col,
                                                   const float* __restrict__ dinv,
                                                   const float* __restrict__ b,
                                                   float* __restrict__ out) {
    int tid = threadIdx.x;
    int sub = tid & 31;
    int n = blockIdx.x * 8 + (tid >> 5);
    float dn = dinv[n];
    const float4* xw4 = (const float4*)xw;
    float4 a = xw4[(size_t)n * 32 + sub];
    float ws = dn * dn;
    float4 acc;
    acc.x = a.x * ws; acc.y = a.y * ws; acc.z = a.z * ws; acc.w = a.w * ws;
    int beg = rowptr[n], end = rowptr[n + 1];
    int e = beg;
    for (; e + 4 <= end; e += 4) {
        int s0 = col[e], s1 = col[e + 1], s2 = col[e + 2], s3 = col[e + 3];
        float w0 = dinv[s0] * dn, w1 = dinv[s1] * dn;
        float w2 = dinv[s2] * dn, w3 = dinv[s3] * dn;
        float4 v0 = xw4[(size_t)s0 * 32 + sub];
        float4 v1 = xw4[(size_t)s1 * 32 + sub];
        float4 v2 = xw4[(size_t)s2 * 32 + sub];
        float4 v3 = xw4[(size_t)s3 * 32 + sub];
        acc.x = fmaf(v0.x, w0, acc.x); acc.y = fmaf(v0.y, w0, acc.y);
        acc.z = fmaf(v0.z, w0, acc.z); acc.w = fmaf(v0.w, w0, acc.w);
        acc.x = fmaf(v1.x, w1, acc.x); acc.y = fmaf(v1.y, w1, acc.y);
        acc.z = fmaf(v1.z, w1, acc.z); acc.w = fmaf(v1.w, w1, acc.w);
        acc.x = fmaf(v2.x, w2, acc.x); acc.y = fmaf(v2.y, w2, acc.y);
        acc.z = fmaf(v2.z, w2, acc.z); acc.w = fmaf(v2.w, w2, acc.w);
        acc.x = fmaf(v3.x, w3, acc.x); acc.y = fmaf(v3.y, w3, acc.y);
        acc.z = fmaf(v3.z, w3, acc.z); acc.w = fmaf(v3.w, w3, acc.w);
    }
    for (; e < end; e++) {
        int s0 = col[e];
        float w0 = dinv[s0] * dn;
        float4 v0 = xw4[(size_t)s0 * 32 + sub];
        acc.x = fmaf(v0.x, w0, acc.x); acc.y = fmaf(v0.y, w0, acc.y);
        acc.z = fmaf(v0.z, w0, acc.z); acc.w = fmaf(v0.w, w0, acc.w);
    }
    float4 b4 = ((const float4*)b)[sub];
    acc.x = fmaxf(acc.x + b4.x, 0.f);
    acc.y = fmaxf(acc.y + b4.y, 0.f);
    acc.z = fmaxf(acc.z + b4.z, 0.f);
    acc.w = fmaxf(acc.w + b4.w, 0.f);
    ((float4*)out)[(size_t)n * 32 + sub] = acc;
}

// ---------------------------------------------------------------- Mamba scan, shuffle-free
// One d-channel per thread (block = all 256 d, one 32-step chunk). All 16 states in
// registers; B/C/D8 LDS reads are wave-broadcasts; the 16-state C-dot is in-register.
// x and y go through transposed LDS tiles (pad 257 -> conflict-free).
__global__ __launch_bounds__(256) void scan_phase1(const float* __restrict__ xst,
                                                   const float* __restrict__ dblt,
                                                   const float* __restrict__ A_log,
                                                   const float* __restrict__ W_dt,
                                                   const float* __restrict__ b_dt,
                                                   float* __restrict__ chkP,
                                                   float* __restrict__ chkH) {
    __shared__ float Tx[CHLEN][257];
    __shared__ float D8s[8][33];
    __shared__ float Bt[CHLEN][20];
    int tid = threadIdx.x;
    int chunk = blockIdx.x;
    int t0 = chunk * CHLEN;
#pragma unroll
    for (int jj = 0; jj < 32; jj++) {
        int lin = tid + jj * 256;
        int dd = lin >> 5, t = lin & 31;
        Tx[t][dd] = xst[(size_t)dd * NN + t0 + t];
    }
    {
        int s = tid >> 5, t = tid & 31;
        D8s[s][t] = dblt[(size_t)s * NN + t0 + t];
    }
#pragma unroll
    for (int jj = 0; jj < 2; jj++) {
        int lin = tid + jj * 256;
        int s = lin >> 5, t = lin & 31;
        Bt[t][s] = dblt[(size_t)(8 + s) * NN + t0 + t];
    }
    int d = tid;
    float wv[8];
#pragma unroll
    for (int k = 0; k < 8; k++) wv[k] = W_dt[k * DI + d];
    float bd = b_dt[d];
    float A[16];
#pragma unroll
    for (int q = 0; q < 4; q++) {
        float4 al = *(const float4*)&A_log[d * DS + q * 4];
        A[q*4+0] = -expf(al.x); A[q*4+1] = -expf(al.y);
        A[q*4+2] = -expf(al.z); A[q*4+3] = -expf(al.w);
    }
    float h[16], P[16];
#pragma unroll
    for (int s = 0; s < 16; s++) { h[s] = 0.f; P[s] = 1.f; }
    __syncthreads();
    for (int t = 0; t < CHLEN; t++) {
        float acc = bd;
#pragma unroll
        for (int k = 0; k < 8; k++) acc = fmaf(D8s[k][t], wv[k], acc);
        float dtv = softplusf(acc);
        float dx = dtv * Tx[t][d];
        float4 b0 = *(const float4*)&Bt[t][0];
        float4 b1 = *(const float4*)&Bt[t][4];
        float4 b2 = *(const float4*)&Bt[t][8];
        float4 b3 = *(const float4*)&Bt[t][12];
        float Bv[16] = {b0.x,b0.y,b0.z,b0.w, b1.x,b1.y,b1.z,b1.w,
                        b2.x,b2.y,b2.z,b2.w, b3.x,b3.y,b3.z,b3.w};
#pragma unroll
        for (int s = 0; s < 16; s++) {
            float a = __expf(dtv * A[s]);
            h[s] = fmaf(a, h[s], dx * Bv[s]);
            P[s] *= a;
        }
    }
    size_t base = (size_t)chunk * 4096 + d * 16;
#pragma unroll
    for (int q = 0; q < 4; q++) {
        float4 vP; vP.x = P[q*4]; vP.y = P[q*4+1]; vP.z = P[q*4+2]; vP.w = P[q*4+3];
        float4 vH; vH.x = h[q*4]; vH.y = h[q*4+1]; vH.z = h[q*4+2]; vH.w = h[q*4+3];
        *(float4*)&chkP[base + q*4] = vP;
        *(float4*)&chkH[base + q*4] = vH;
    }
}

// phase2: serial over chunks; init written IN-PLACE over chkP (read-before-write;
// no __restrict__; manual prefetch pipeline keeps loads ahead of the store stream).
__global__ void scan_phase2(const float* chkP, const float* chkH, float* init) {
    int idx = blockIdx.x * blockDim.x + threadIdx.x;  // 4096 total
    float h = 0.f;
    float p[8], q[8], pn[8], qn[8];
#pragma unroll
    for (int j = 0; j < 8; j++) {
        p[j] = chkP[j * 4096 + idx];
        q[j] = chkH[j * 4096 + idx];
    }
    for (int c0 = 0; c0 < NCH; c0 += 8) {
        if (c0 + 8 < NCH) {
#pragma unroll
            for (int j = 0; j < 8; j++) {
                pn[j] = chkP[(c0 + 8 + j) * 4096 + idx];
                qn[j] = chkH[(c0 + 8 + j) * 4096 + idx];
            }
        }
#pragma unroll
        for (int j = 0; j < 8; j++) {
            init[(c0 + j) * 4096 + idx] = h;
            h = fmaf(p[j], h, q[j]);
        }
#pragma unroll
        for (int j = 0; j < 8; j++) { p[j] = pn[j]; q[j] = qn[j]; }
    }
}

// phase3: same structure as phase1 + C-dot in registers (no shuffles) + y via LDS
// transpose; silu(z) applied at the coalesced write from xz^T z-rows.
__global__ __launch_bounds__(256) void scan_phase3(const float* __restrict__ xst,
                                                   const float* __restrict__ dblt,
                                                   const float* __restrict__ A_log,
                                                   const float* __restrict__ W_dt,
                                                   const float* __restrict__ b_dt,
                                                   const float* __restrict__ init,
                                                   const float* __restrict__ D_p,
                                                   const float* __restrict__ xzt,
                                                   float* __restrict__ yt) {
    __shared__ float Tx[CHLEN][257];
    __shared__ float Yl[CHLEN][257];
    __shared__ float D8s[8][33];
    __shared__ float Bt[CHLEN][20];
    __shared__ float Ctt[CHLEN][20];
    int tid = threadIdx.x;
    int chunk = blockIdx.x;
    int t0 = chunk * CHLEN;
#pragma unroll
    for (int jj = 0; jj < 32; jj++) {
        int lin = tid + jj * 256;
        int dd = lin >> 5, t = lin & 31;
        Tx[t][dd] = xst[(size_t)dd * NN + t0 + t];
    }
    {
        int s = tid >> 5, t = tid & 31;
        D8s[s][t] = dblt[(size_t)s * NN + t0 + t];
    }
#pragma unroll
    for (int jj = 0; jj < 2; jj++) {
        int lin = tid + jj * 256;
        int s = lin >> 5, t = lin & 31;
        Bt[t][s]  = dblt[(size_t)(8 + s) * NN + t0 + t];
        Ctt[t][s] = dblt[(size_t)(24 + s) * NN + t0 + t];
    }
    int d = tid;
    float wv[8];
#pragma unroll
    for (int k = 0; k < 8; k++) wv[k] = W_dt[k * DI + d];
    float bd = b_dt[d];
    float Dd = D_p[d];
    float A[16];
#pragma unroll
    for (int q = 0; q < 4; q++) {
        float4 al = *(const float4*)&A_log[d * DS + q * 4];
        A[q*4+0] = -expf(al.x); A[q*4+1] = -expf(al.y);
        A[q*4+2] = -expf(al.z); A[q*4+3] = -expf(al.w);
    }
    float h[16];
    size_t base = (size_t)chunk * 4096 + d * 16;
#pragma unroll
    for (int q = 0; q < 4; q++) {
        float4 vi = *(const float4*)&init[base + q * 4];
        h[q*4+0] = vi.x; h[q*4+1] = vi.y; h[q*4+2] = vi.z; h[q*4+3] = vi.w;
    }
    __syncthreads();
    for (int t = 0; t < CHLEN; t++) {
        float acc = bd;
#pragma unroll
        for (int k = 0; k < 8; k++) acc = fmaf(D8s[k][t], wv[k], acc);
        float dtv = softplusf(acc);
        float x = Tx[t][d];
        float dx = dtv * x;
        float4 b0 = *(const float4*)&Bt[t][0];
        float4 b1 = *(const float4*)&Bt[t][4];
        float4 b2 = *(const float4*)&Bt[t][8];
        float4 b3 = *(const float4*)&Bt[t][12];
        float4 c0 = *(const float4*)&Ctt[t][0];
        float4 c1 = *(const float4*)&Ctt[t][4];
        float4 c2 = *(const float4*)&Ctt[t][8];
        float4 c3 = *(const float4*)&Ctt[t][12];
        float Bv[16] = {b0.x,b0.y,b0.z,b0.w, b1.x,b1.y,b1.z,b1.w,
                        b2.x,b2.y,b2.z,b2.w, b3.x,b3.y,b3.z,b3.w};
        float Cv[16] = {c0.x,c0.y,c0.z,c0.w, c1.x,c1.y,c1.z,c1.w,
                        c2.x,c2.y,c2.z,c2.w, c3.x,c3.y,c3.z,c3.w};
        float y = 0.f;
#pragma unroll
        for (int s = 0; s < 16; s++) {
            float a = __expf(dtv * A[s]);
            h[s] = fmaf(a, h[s], dx * Bv[s]);
            y = fmaf(h[s], Cv[s], y);
        }
        Yl[t][d] = fmaf(Dd, x, y);
    }
    __syncthreads();
#pragma unroll
    for (int jj = 0; jj < 32; jj++) {
        int lin = tid + jj * 256;
        int dd = lin >> 5, t = lin & 31;
        float z = xzt[(size_t)(256 + dd) * NN + t0 + t];
        yt[(size_t)dd * NN + t0 + t] = Yl[t][dd] * siluf(z);
    }
}

// ---------------------------------------------------------------- output heads (ge_norm folded in)
__global__ void heads_kernel(const float* __restrict__ ge, const int* __restrict__ counts,
                             const float* Wc, const float* bc, const float* Wh, const float* bh,
                             const float* Wt, const float* bt, const float* Wp1, const float* bp1,
                             const float* Wp2, const float* bp2, const float* Wd, const float* bd,
                             const float* Ws, const float* bs, float* __restrict__ out) {
    int col = blockIdx.x * blockDim.x + threadIdx.x;
    int b = blockIdx.y;
    if (col >= OUTW) return;
    const float* W; const float* bi; int lc, w;
    if (col < 1)         { W = Wc;  bi = bc;  lc = col;        w = 1; }
    else if (col < 5)    { W = Wh;  bi = bh;  lc = col - 1;    w = 4; }
    else if (col < 8)    { W = Wt;  bi = bt;  lc = col - 5;    w = 3; }
    else if (col < 520)  { W = Wp1; bi = bp1; lc = col - 8;    w = 512; }
    else if (col < 1032) { W = Wp2; bi = bp2; lc = col - 520;  w = 512; }
    else if (col < 1544) { W = Wd;  bi = bd;  lc = col - 1032; w = 512; }
    else                 { W = Ws;  bi = bs;  lc = col - 1544; w = 8; }
    float scale = 1.f / fmaxf((float)counts[b], 1.f);
    float dot = 0.f;
#pragma unroll 8
    for (int f = 0; f < HH; f++) dot = fmaf(ge[b * HH + f], W[f * w + lc], dot);
    out[(size_t)b * OUTW + col] = bi[lc] + scale * dot;
}

// ---------------------------------------------------------------- launch
extern "C" void kernel_launch(void* const* d_in, const int* in_sizes, int n_in,
                              void* d_out, int out_size, void* d_ws, size_t ws_size,
                              hipStream_t stream) {
    const float* nf      = (const float*)d_in[0];
    const int*   ei      = (const int*)d_in[1];
    const int*   batch   = (const int*)d_in[2];
    const float* W_in    = (const float*)d_in[3];
    const float* b_in    = (const float*)d_in[4];
    const float* W_g1    = (const float*)d_in[5];
    const float* b_g1    = (const float*)d_in[6];
    const float* W_g2    = (const float*)d_in[7];
    const float* b_g2    = (const float*)d_in[8];
    const float* W_inproj= (const float*)d_in[9];
    const float* conv_w  = (const float*)d_in[10];
    const float* conv_b  = (const float*)d_in[11];
    const float* W_xproj = (const float*)d_in[12];
    const float* W_dt    = (const float*)d_in[13];
    const float* b_dt    = (const float*)d_in[14];
    const float* A_log   = (const float*)d_in[15];
    const float* D_p     = (const float*)d_in[16];
    const float* W_out   = (const float*)d_in[17];
    const float* gamma   = (const float*)d_in[18];
    const float* beta    = (const float*)d_in[19];
    const float* Wc = (const float*)d_in[20]; const float* bc = (const float*)d_in[21];
    const float* Wh = (const float*)d_in[22]; const float* bh = (const float*)d_in[23];
    const float* Wt = (const float*)d_in[24]; const float* bt = (const float*)d_in[25];
    const float* Wp1= (const float*)d_in[26]; const float* bp1= (const float*)d_in[27];
    const float* Wp2= (const float*)d_in[28]; const float* bp2= (const float*)d_in[29];
    const float* Wd = (const float*)d_in[30]; const float* bd = (const float*)d_in[31];
    const float* Ws = (const float*)d_in[32]; const float* bs = (const float*)d_in[33];

    const int* e_src = ei;
    const int* e_dst = ei + EE;

    // workspace layout (floats, then ints)
    float* w = (float*)d_ws;
    size_t o = 0;
    float* F0   = w + o; o += (size_t)NN * HH;   // dead during scan -> CHP (512*4096 = NN*HH exactly)
    float* F1   = w + o; o += (size_t)NN * HH;   // dead during scan -> CHH
    float* F2   = w + o; o += (size_t)NN * HH;
    float* XZT  = w + o; o += (size_t)NN * 512;  // xz TRANSPOSED [512][NN]; x-rows dead after dblt:
    float* YT   = XZT;                            //   y^T [DI][NN] (aliases x-rows; z-rows still live)
    float* XST  = w + o; o += (size_t)NN * DI;   // x (conv+silu), transposed [DI][NN] (written by dblt)
    float* DBLT = w + o; o += (size_t)NN * 40;   // [40][NN]; 0..7 = dt-proj^T, 8..23 = B^T, 24..39 = C^T
    float* GE   = w + o; o += BB * HH;
    float* DINV = w + o; o += NN;
    int* ip = (int*)(w + o);
    int* CNT    = ip; ip += NN;
    int* ROWPTR = ip; ip += NN + 1;
    int* CURSOR = ip; ip += NN;
    int* COL    = ip; ip += EE;
    int* COUNTS = ip; ip += BB;

    // overlays (regions dead during the scan)
    float* CHP  = F0;                         // NCH*4096 = 2M floats (== F0 size exactly)
    float* CHH  = F1;                         // 2M floats
    float* INI  = CHP;                        // init written in-place over chkP (phase2)

    // zero scratch (single kernel instead of 3 memsets)
    zero_kernel<<<(NN + 255) / 256, 256, 0, stream>>>(CNT, GE, COUNTS);

    // CSR build
    deg_kernel<<<EE / 256, 256, 0, stream>>>(e_dst, CNT);
    prefix_kernel<<<1, 1024, 0, stream>>>(CNT, ROWPTR, CURSOR, DINV);
    scatter_kernel<<<EE / 256, 256, 0, stream>>>(e_src, e_dst, CURSOR, COL);

    // xw1 = relu(nf @ W_in + b_in) @ W_g1  (h0 never materialized)
    gemm_in_g1<<<dim3(2, NN / 64), 256, 0, stream>>>(nf, W_in, b_in, W_g1, F1);
    gcn_gather4<<<NN / 8, 256, 0, stream>>>(F1, ROWPTR, COL, DINV, b_g1, F0);
    // GCN layer 2
    gemm_k<<<dim3(2, NN / 64), 256, 0, stream>>>(F0, W_g2, nullptr, F1, NN, HH, HH, 0);
    gcn_gather4<<<NN / 8, 256, 0, stream>>>(F1, ROWPTR, COL, DINV, b_g2, F2);  // F2 = h_gnn

    // xz^T = (h_gnn @ W_inproj)^T  (transposed store: all consumers want [512][NN])
    gemm_big512_t<<<dim3(4, NN / 128), 512, 0, stream>>>(F2, W_inproj, XZT, NN, 512, HH);
    // dbl = conv_silu(xz_x) @ W_xproj with conv fused; also materializes XST
    gemm_xz_dblt<<<NN / 64, 256, 0, stream>>>(XZT, W_xproj, conv_w, conv_b, XST, DBLT);

    // Mamba scan, shuffle-free: one d per thread, 16 states in registers
    scan_phase1<<<NCH, 256, 0, stream>>>(XST, DBLT, A_log, W_dt, b_dt, CHP, CHH);
    scan_phase2<<<16, 256, 0, stream>>>(CHP, CHH, INI);
    scan_phase3<<<NCH, 256, 0, stream>>>(XST, DBLT, A_log, W_dt, b_dt, INI, D_p, XZT, YT);

    // h_mamba = y @ W_out; + h_gnn; LayerNorm; pooled directly into GE (h_final never stored)
    gemm_at_ln_pool<<<NN / 32, 256, 0, stream>>>(YT, W_out, F2, gamma, beta, batch, GE, COUNTS);

    // heads (ge_norm folded in)
    heads_kernel<<<dim3((OUTW + 127) / 128, BB), 128, 0, stream>>>(
        GE, COUNTS, Wc, bc, Wh, bh, Wt, bt, Wp1, bp1, Wp2, bp2, Wd, bd, Ws, bs, (float*)d_out);
}

// Round 7
// 398.173 us; speedup vs baseline: 1.0520x; 1.0520x over previous
//
#include <hip/hip_runtime.h>
#include <math.h>

#define NN 16384
#define EE 262144
#define FF 32
#define HH 128
#define BB 16
#define DI 256
#define DS 16
#define DC 4
#define DTR 8
#define OUTW 1552
#define NCH 512
#define CHLEN 32    // NCH*CHLEN == NN

// ---------------------------------------------------------------- utilities
__device__ __forceinline__ float siluf(float v) { return v / (1.f + __expf(-v)); }
__device__ __forceinline__ float softplusf(float v) {
    return fmaxf(v, 0.f) + __logf(1.f + __expf(-fabsf(v)));
}

// ---------------------------------------------------------------- zero scratch (replaces 3 memsets)
__global__ void zero_kernel(int* __restrict__ cnt, float* __restrict__ ge,
                            int* __restrict__ counts) {
    int idx = blockIdx.x * blockDim.x + threadIdx.x;
    if (idx < NN) cnt[idx] = 0;
    if (idx < BB * HH) ge[idx] = 0.f;
    if (idx < BB) counts[idx] = 0;
}

// ---------------------------------------------------------------- CSR build
__global__ void deg_kernel(const int* __restrict__ dst, int* __restrict__ cnt) {
    int e = blockIdx.x * blockDim.x + threadIdx.x;
    if (e < EE) atomicAdd(&cnt[dst[e]], 1);
}

__global__ __launch_bounds__(1024) void prefix_kernel(const int* __restrict__ cnt,
                                                      int* __restrict__ rowptr,
                                                      int* __restrict__ cursor,
                                                      float* __restrict__ dinv) {
    __shared__ int part[1024];
    int tid = threadIdx.x;
    int4 c4[4];
#pragma unroll
    for (int j = 0; j < 4; j++) c4[j] = ((const int4*)cnt)[tid * 4 + j];
    int v[16] = {c4[0].x, c4[0].y, c4[0].z, c4[0].w, c4[1].x, c4[1].y, c4[1].z, c4[1].w,
                 c4[2].x, c4[2].y, c4[2].z, c4[2].w, c4[3].x, c4[3].y, c4[3].z, c4[3].w};
    int s = 0;
#pragma unroll
    for (int j = 0; j < 16; j++) s += v[j];
    part[tid] = s;
    __syncthreads();
    for (int off = 1; off < 1024; off <<= 1) {
        int t = (tid >= off) ? part[tid - off] : 0;
        __syncthreads();
        part[tid] += t;
        __syncthreads();
    }
    int running = part[tid] - s;
    int rp[16];
    float dv[16];
#pragma unroll
    for (int j = 0; j < 16; j++) {
        rp[j] = running;
        running += v[j];
        dv[j] = rsqrtf((float)(v[j] + 1));  // +1 self loop
    }
#pragma unroll
    for (int j = 0; j < 4; j++) {
        int4 r4; r4.x = rp[j*4]; r4.y = rp[j*4+1]; r4.z = rp[j*4+2]; r4.w = rp[j*4+3];
        ((int4*)rowptr)[tid * 4 + j] = r4;
        ((int4*)cursor)[tid * 4 + j] = r4;
        float4 d4; d4.x = dv[j*4]; d4.y = dv[j*4+1]; d4.z = dv[j*4+2]; d4.w = dv[j*4+3];
        ((float4*)dinv)[tid * 4 + j] = d4;
    }
    if (tid == 1023) rowptr[NN] = part[1023];
}

__global__ void scatter_kernel(const int* __restrict__ src, const int* __restrict__ dst,
                               int* __restrict__ cursor, int* __restrict__ col) {
    int e = blockIdx.x * blockDim.x + threadIdx.x;
    if (e < EE) {
        int d = dst[e];
        int pos = atomicAdd(&cursor[d], 1);
        col[pos] = src[e];
    }
}

// ---------------------------------------------------------------- GEMM (fp32, 64x64 tile)
__global__ __launch_bounds__(256) void gemm_k(const float* __restrict__ A,
                                              const float* __restrict__ B,
                                              const float* __restrict__ bias,
                                              float* __restrict__ C,
                                              int M, int Nn, int K, int act) {
    __shared__ float As[16][68];
    __shared__ float Bs[16][68];
    int tid = threadIdx.x;
    int m0 = blockIdx.y * 64;
    int n0 = blockIdx.x * 64;
    int ty = tid >> 4, tx = tid & 15;
    float acc[4][4] = {{0.f}};
    for (int k0 = 0; k0 < K; k0 += 16) {
#pragma unroll
        for (int l = 0; l < 4; l++) {
            int idx = tid + l * 256;
            int i = idx >> 4, j = idx & 15;
            As[j][i] = A[(size_t)(m0 + i) * K + k0 + j];
        }
#pragma unroll
        for (int l = 0; l < 4; l++) {
            int idx = tid + l * 256;
            int i = idx >> 6, j = idx & 63;
            int n = n0 + j;
            Bs[i][j] = (n < Nn) ? B[(size_t)(k0 + i) * Nn + n] : 0.f;
        }
        __syncthreads();
#pragma unroll
        for (int kk = 0; kk < 16; kk++) {
            float4 a4 = *(const float4*)&As[kk][ty * 4];
            float4 b4 = *(const float4*)&Bs[kk][tx * 4];
            float av[4] = {a4.x, a4.y, a4.z, a4.w};
            float bv[4] = {b4.x, b4.y, b4.z, b4.w};
#pragma unroll
            for (int r = 0; r < 4; r++)
#pragma unroll
                for (int c = 0; c < 4; c++) acc[r][c] = fmaf(av[r], bv[c], acc[r][c]);
        }
        __syncthreads();
    }
    int nb = n0 + tx * 4;
    if (nb < Nn) {
        float4 bi4 = {0.f, 0.f, 0.f, 0.f};
        if (bias) bi4 = *(const float4*)&bias[nb];
#pragma unroll
        for (int r = 0; r < 4; r++) {
            int m = m0 + ty * 4 + r;
            float4 v;
            v.x = acc[r][0] + bi4.x; v.y = acc[r][1] + bi4.y;
            v.z = acc[r][2] + bi4.z; v.w = acc[r][3] + bi4.w;
            if (act == 1) {
                v.x = fmaxf(v.x, 0.f); v.y = fmaxf(v.y, 0.f);
                v.z = fmaxf(v.z, 0.f); v.w = fmaxf(v.w, 0.f);
            }
            *(float4*)&C[(size_t)m * Nn + nb] = v;
        }
    }
}

// ---------------------------------------------------------------- fused relu(nf@W_in+b) @ W_g1
union SMemIn {
    struct { float Ns[64][33]; float Ws[32][132]; } s1;   // step-1 staging
    float Bs[16][68];                                     // step-2 W_g1 chunk
};

__global__ __launch_bounds__(256) void gemm_in_g1(const float* __restrict__ nf,
                                                  const float* __restrict__ W_in,
                                                  const float* __restrict__ b_in,
                                                  const float* __restrict__ W_g1,
                                                  float* __restrict__ out) {
    __shared__ SMemIn sm;
    __shared__ float Hs[128][68];   // h^T: Hs[k][m]
    int tid = threadIdx.x;
    int m0 = blockIdx.y * 64;
    int n0 = blockIdx.x * 64;
    int ty = tid >> 4, tx = tid & 15;
#pragma unroll
    for (int l = 0; l < 2; l++) {
        int q = tid + l * 256;
        int r = q >> 3, c4 = (q & 7) * 4;
        *(float4*)&sm.s1.Ns[r][c4] = *(const float4*)&nf[(size_t)(m0 + r) * FF + c4];
    }
#pragma unroll
    for (int l = 0; l < 4; l++) {
        int q = tid + l * 256;
        int r = q >> 5, c4 = (q & 31) * 4;
        *(float4*)&sm.s1.Ws[r][c4] = *(const float4*)&W_in[(size_t)r * HH + c4];
    }
    __syncthreads();
    {
        float4 b0 = *(const float4*)&b_in[tx * 4];
        float4 b1 = *(const float4*)&b_in[64 + tx * 4];
        float hacc[4][8];
#pragma unroll
        for (int r = 0; r < 4; r++) {
            hacc[r][0] = b0.x; hacc[r][1] = b0.y; hacc[r][2] = b0.z; hacc[r][3] = b0.w;
            hacc[r][4] = b1.x; hacc[r][5] = b1.y; hacc[r][6] = b1.z; hacc[r][7] = b1.w;
        }
#pragma unroll
        for (int k = 0; k < FF; k++) {
            float av[4];
#pragma unroll
            for (int r = 0; r < 4; r++) av[r] = sm.s1.Ns[ty * 4 + r][k];
            float wv[8];
#pragma unroll
            for (int c = 0; c < 4; c++) {
                wv[c]     = sm.s1.Ws[k][tx * 4 + c];
                wv[c + 4] = sm.s1.Ws[k][64 + tx * 4 + c];
            }
#pragma unroll
            for (int r = 0; r < 4; r++)
#pragma unroll
                for (int c = 0; c < 8; c++) hacc[r][c] = fmaf(av[r], wv[c], hacc[r][c]);
        }
#pragma unroll
        for (int r = 0; r < 4; r++)
#pragma unroll
            for (int c = 0; c < 4; c++) {
                Hs[tx * 4 + c][ty * 4 + r]      = fmaxf(hacc[r][c], 0.f);
                Hs[64 + tx * 4 + c][ty * 4 + r] = fmaxf(hacc[r][c + 4], 0.f);
            }
    }
    __syncthreads();
    float acc[4][4] = {{0.f}};
    for (int k0 = 0; k0 < HH; k0 += 16) {
        *(float4*)&sm.Bs[tid >> 4][(tid & 15) * 4] =
            *(const float4*)&W_g1[(size_t)(k0 + (tid >> 4)) * HH + n0 + (tid & 15) * 4];
        __syncthreads();
#pragma unroll
        for (int kk = 0; kk < 16; kk++) {
            float4 a4 = *(const float4*)&Hs[k0 + kk][ty * 4];
            float4 b4 = *(const float4*)&sm.Bs[kk][tx * 4];
            float av[4] = {a4.x, a4.y, a4.z, a4.w};
            float bv[4] = {b4.x, b4.y, b4.z, b4.w};
#pragma unroll
            for (int r = 0; r < 4; r++)
#pragma unroll
                for (int c = 0; c < 4; c++) acc[r][c] = fmaf(av[r], bv[c], acc[r][c]);
        }
        __syncthreads();
    }
#pragma unroll
    for (int r = 0; r < 4; r++) {
        int m = m0 + ty * 4 + r;
        float4 v;
        v.x = acc[r][0]; v.y = acc[r][1]; v.z = acc[r][2]; v.w = acc[r][3];
        *(float4*)&out[(size_t)m * HH + n0 + tx * 4] = v;
    }
}

// ---------------------------------------------------------------- big-tile GEMM, 512 threads, TRANSPOSED output
__global__ __launch_bounds__(512, 4) void gemm_big512_t(const float* __restrict__ A,
                                                        const float* __restrict__ B,
                                                        float* __restrict__ CT,
                                                        int M, int Nn, int K) {
    __shared__ float As[16][132];
    __shared__ float Bs[16][132];
    int tid = threadIdx.x;
    int m0 = blockIdx.y * 128;
    int n0 = blockIdx.x * 128;
    int ty = tid >> 4;          // 0..31 -> m rows ty*4..ty*4+3
    int tx = tid & 15;          // n cols tx*4 and 64+tx*4
    float acc[4][8] = {{0.f}};
    for (int k0 = 0; k0 < K; k0 += 16) {
        {   // A: 128 m x 16 k, one float4 per thread -> As[k][m]
            int m = tid >> 2;
            int kc = (tid & 3) * 4;
            float4 a = *(const float4*)&A[(size_t)(m0 + m) * K + k0 + kc];
            As[kc + 0][m] = a.x; As[kc + 1][m] = a.y;
            As[kc + 2][m] = a.z; As[kc + 3][m] = a.w;
        }
        {   // B: 16 k x 128 n, one float4 per thread
            int krow = tid >> 5;
            int c4 = (tid & 31) * 4;
            *(float4*)&Bs[krow][c4] = *(const float4*)&B[(size_t)(k0 + krow) * Nn + n0 + c4];
        }
        __syncthreads();
#pragma unroll
        for (int kk = 0; kk < 16; kk++) {
            float4 a4 = *(const float4*)&As[kk][ty * 4];
            float4 b0 = *(const float4*)&Bs[kk][tx * 4];
            float4 b1 = *(const float4*)&Bs[kk][64 + tx * 4];
            float av[4] = {a4.x, a4.y, a4.z, a4.w};
            float bv[8] = {b0.x, b0.y, b0.z, b0.w, b1.x, b1.y, b1.z, b1.w};
#pragma unroll
            for (int r = 0; r < 4; r++)
#pragma unroll
                for (int c = 0; c < 8; c++) acc[r][c] = fmaf(av[r], bv[c], acc[r][c]);
        }
        __syncthreads();
    }
    // transposed store: CT[n][m]
#pragma unroll
    for (int cc = 0; cc < 4; cc++) {
        float4 v;
        v.x = acc[0][cc]; v.y = acc[1][cc]; v.z = acc[2][cc]; v.w = acc[3][cc];
        *(float4*)&CT[(size_t)(n0 + tx * 4 + cc) * NN + m0 + ty * 4] = v;
        float4 u;
        u.x = acc[0][cc + 4]; u.y = acc[1][cc + 4]; u.z = acc[2][cc + 4]; u.w = acc[3][cc + 4];
        *(float4*)&CT[(size_t)(n0 + 64 + tx * 4 + cc) * NN + m0 + ty * 4] = u;
    }
}

// ---------------------------------------------------------------- conv + silu over transposed xz
__global__ __launch_bounds__(256) void conv_silu_rows(const float* __restrict__ xzt,
                                                      const float* __restrict__ cw,
                                                      const float* __restrict__ cb,
                                                      float* __restrict__ xst,
                                                      float* __restrict__ szt) {
    int d = blockIdx.y;                       // 0..511 (x rows then z rows)
    int tg = blockIdx.x * 1024 + threadIdx.x * 4;
    const float* row = xzt + (size_t)d * NN;
    float4 cur = *(const float4*)&row[tg];
    if (d < DI) {
        float4 prev;
        if (tg == 0) { prev.x = 0.f; prev.y = 0.f; prev.z = 0.f; prev.w = 0.f; }
        else prev = *(const float4*)&row[tg - 4];
        float w0 = cw[d * DC + 0], w1 = cw[d * DC + 1];
        float w2 = cw[d * DC + 2], w3 = cw[d * DC + 3];
        float b = cb[d];
        float4 o;
        o.x = siluf(b + w0 * prev.y + w1 * prev.z + w2 * prev.w + w3 * cur.x);
        o.y = siluf(b + w0 * prev.z + w1 * prev.w + w2 * cur.x + w3 * cur.y);
        o.z = siluf(b + w0 * prev.w + w1 * cur.x + w2 * cur.y + w3 * cur.z);
        o.w = siluf(b + w0 * cur.x + w1 * cur.y + w2 * cur.z + w3 * cur.w);
        *(float4*)&xst[(size_t)d * NN + tg] = o;
    } else {
        float4 o;
        o.x = siluf(cur.x); o.y = siluf(cur.y); o.z = siluf(cur.z); o.w = siluf(cur.w);
        *(float4*)&szt[(size_t)(d - DI) * NN + tg] = o;
    }
}

// ---------------------------------------------------------------- xproj GEMM (A^T) + transposed output
__global__ __launch_bounds__(256) void gemm_at_dblt(const float* __restrict__ AT,
                                                    const float* __restrict__ B,
                                                    float* __restrict__ dblt) {
    __shared__ float As[16][68];
    __shared__ float Bs[16][68];
    __shared__ float Ct[64][41];
    int tid = threadIdx.x;
    int m0 = blockIdx.x * 64;
    int ty = tid >> 4, tx = tid & 15;
    float acc[4][4] = {{0.f}};
    for (int k0 = 0; k0 < DI; k0 += 16) {
#pragma unroll
        for (int l = 0; l < 4; l++) {
            int idx = tid + l * 256;
            int kk = idx >> 6, i = idx & 63;
            As[kk][i] = AT[(size_t)(k0 + kk) * NN + m0 + i];
        }
#pragma unroll
        for (int l = 0; l < 4; l++) {
            int idx = tid + l * 256;
            int i = idx >> 6, j = idx & 63;
            Bs[i][j] = (j < 40) ? B[(size_t)(k0 + i) * 40 + j] : 0.f;
        }
        __syncthreads();
#pragma unroll
        for (int kk = 0; kk < 16; kk++) {
            float4 a4 = *(const float4*)&As[kk][ty * 4];
            float4 b4 = *(const float4*)&Bs[kk][tx * 4];
            float av[4] = {a4.x, a4.y, a4.z, a4.w};
            float bv[4] = {b4.x, b4.y, b4.z, b4.w};
#pragma unroll
            for (int r = 0; r < 4; r++)
#pragma unroll
                for (int c = 0; c < 4; c++) acc[r][c] = fmaf(av[r], bv[c], acc[r][c]);
        }
        __syncthreads();
    }
    if (tx * 4 < 40) {
#pragma unroll
        for (int r = 0; r < 4; r++) {
            int m = ty * 4 + r;
            Ct[m][tx * 4 + 0] = acc[r][0];
            Ct[m][tx * 4 + 1] = acc[r][1];
            Ct[m][tx * 4 + 2] = acc[r][2];
            Ct[m][tx * 4 + 3] = acc[r][3];
        }
    }
    __syncthreads();
#pragma unroll
    for (int l = 0; l < 10; l++) {
        int idx = tid + l * 256;
        int n = idx >> 6, m = idx & 63;
        dblt[(size_t)n * NN + m0 + m] = Ct[m][n];
    }
}

// ---------------------------------------------------------------- fused W_out GEMM + add + LayerNorm + POOL
__global__ __launch_bounds__(256) void gemm_at_ln_pool(const float* __restrict__ AT,
                                                       const float* __restrict__ B,
                                                       const float* __restrict__ hg,
                                                       const float* __restrict__ gamma,
                                                       const float* __restrict__ beta,
                                                       const int* __restrict__ batch,
                                                       float* __restrict__ ge,
                                                       int* __restrict__ counts) {
    __shared__ float As[16][36];
    __shared__ float Bs[16][132];
    __shared__ float lnb[32][132];
    __shared__ int gb[32];
    int tid = threadIdx.x;
    int m0 = blockIdx.x * 32;
    int ty = tid >> 4, tx = tid & 15;
    float acc[2][8] = {{0.f}};
    for (int k0 = 0; k0 < 256; k0 += 16) {
        {
            int idx = tid * 2;
            int kk = idx >> 5, i = idx & 31;
            As[kk][i] = AT[(size_t)(k0 + kk) * NN + m0 + i];
            As[kk][i + 1] = AT[(size_t)(k0 + kk) * NN + m0 + i + 1];
        }
        {
            int krow = tid >> 4;
            int c8 = (tid & 15) * 8;
            const float* bp = &B[(size_t)(k0 + krow) * HH + c8];
            *(float4*)&Bs[krow][c8] = *(const float4*)bp;
            *(float4*)&Bs[krow][c8 + 4] = *(const float4*)(bp + 4);
        }
        __syncthreads();
#pragma unroll
        for (int kk = 0; kk < 16; kk++) {
            float a0 = As[kk][ty * 2];
            float a1 = As[kk][ty * 2 + 1];
            float4 b0 = *(const float4*)&Bs[kk][tx * 4];
            float4 b1 = *(const float4*)&Bs[kk][64 + tx * 4];
            float bv[8] = {b0.x, b0.y, b0.z, b0.w, b1.x, b1.y, b1.z, b1.w};
#pragma unroll
            for (int c = 0; c < 8; c++) {
                acc[0][c] = fmaf(a0, bv[c], acc[0][c]);
                acc[1][c] = fmaf(a1, bv[c], acc[1][c]);
            }
        }
        __syncthreads();
    }
    if (tid < 32) gb[tid] = batch[m0 + tid];
    float4 g0 = *(const float4*)&gamma[tx * 4];
    float4 g1 = *(const float4*)&gamma[64 + tx * 4];
    float4 be0 = *(const float4*)&beta[tx * 4];
    float4 be1 = *(const float4*)&beta[64 + tx * 4];
    float gv[8] = {g0.x, g0.y, g0.z, g0.w, g1.x, g1.y, g1.z, g1.w};
    float bv[8] = {be0.x, be0.y, be0.z, be0.w, be1.x, be1.y, be1.z, be1.w};
#pragma unroll
    for (int r = 0; r < 2; r++) {
        int m = m0 + ty * 2 + r;
        float4 h0 = *(const float4*)&hg[(size_t)m * HH + tx * 4];
        float4 h1 = *(const float4*)&hg[(size_t)m * HH + 64 + tx * 4];
        float v[8] = {acc[r][0] + h0.x, acc[r][1] + h0.y, acc[r][2] + h0.z, acc[r][3] + h0.w,
                      acc[r][4] + h1.x, acc[r][5] + h1.y, acc[r][6] + h1.z, acc[r][7] + h1.w};
        float sum = 0.f;
#pragma unroll
        for (int c = 0; c < 8; c++) sum += v[c];
        sum += __shfl_xor(sum, 1); sum += __shfl_xor(sum, 2);
        sum += __shfl_xor(sum, 4); sum += __shfl_xor(sum, 8);
        float mu = sum * (1.f / 128.f);
        float vs = 0.f;
#pragma unroll
        for (int c = 0; c < 8; c++) { float dd = v[c] - mu; vs += dd * dd; }
        vs += __shfl_xor(vs, 1); vs += __shfl_xor(vs, 2);
        vs += __shfl_xor(vs, 4); vs += __shfl_xor(vs, 8);
        float inv = rsqrtf(vs * (1.f / 128.f) + 1e-5f);
        int lr = ty * 2 + r;
        float4 o0, o1;
        o0.x = (v[0] - mu) * inv * gv[0] + bv[0];
        o0.y = (v[1] - mu) * inv * gv[1] + bv[1];
        o0.z = (v[2] - mu) * inv * gv[2] + bv[2];
        o0.w = (v[3] - mu) * inv * gv[3] + bv[3];
        o1.x = (v[4] - mu) * inv * gv[4] + bv[4];
        o1.y = (v[5] - mu) * inv * gv[5] + bv[5];
        o1.z = (v[6] - mu) * inv * gv[6] + bv[6];
        o1.w = (v[7] - mu) * inv * gv[7] + bv[7];
        *(float4*)&lnb[lr][tx * 4] = o0;
        *(float4*)&lnb[lr][64 + tx * 4] = o1;
    }
    __syncthreads();
    if (tid < HH) {
        int f = tid;
        int gcur = gb[0];
        float acc2 = 0.f;
        int cnt = 0;
#pragma unroll 4
        for (int i = 0; i < 32; i++) {
            int g = gb[i];
            if (g != gcur) {
                atomicAdd(&ge[gcur * HH + f], acc2);
                if (f == 0) atomicAdd(&counts[gcur], cnt);
                acc2 = 0.f; cnt = 0; gcur = g;
            }
            acc2 += lnb[i][f];
            cnt++;
        }
        atomicAdd(&ge[gcur * HH + f], acc2);
        if (f == 0) atomicAdd(&counts[gcur], cnt);
    }
}

// ---------------------------------------------------------------- GCN gather, float4, 4-edge unroll
__global__ __launch_bounds__(256) void gcn_gather4(const float* __restrict__ xw,
                                                   const int* __restrict__ rowptr,
                                                   const int* __restrict__ col,
                                                   const float* __restrict__ dinv,
                                                   const float* __restrict__ b,
                                                   float* __restrict__ out) {
    int tid = threadIdx.x;
    int sub = tid & 31;
    int n = blockIdx.x * 8 + (tid >> 5);
    float dn = dinv[n];
    const float4* xw4 = (const float4*)xw;
    float4 a = xw4[(size_t)n * 32 + sub];
    float ws = dn * dn;
    float4 acc;
    acc.x = a.x * ws; acc.y = a.y * ws; acc.z = a.z * ws; acc.w = a.w * ws;
    int beg = rowptr[n], end = rowptr[n + 1];
    int e = beg;
    for (; e + 4 <= end; e += 4) {
        int s0 = col[e], s1 = col[e + 1], s2 = col[e + 2], s3 = col[e + 3];
        float w0 = dinv[s0] * dn, w1 = dinv[s1] * dn;
        float w2 = dinv[s2] * dn, w3 = dinv[s3] * dn;
        float4 v0 = xw4[(size_t)s0 * 32 + sub];
        float4 v1 = xw4[(size_t)s1 * 32 + sub];
        float4 v2 = xw4[(size_t)s2 * 32 + sub];
        float4 v3 = xw4[(size_t)s3 * 32 + sub];
        acc.x = fmaf(v0.x, w0, acc.x); acc.y = fmaf(v0.y, w0, acc.y);
        acc.z = fmaf(v0.z, w0, acc.z); acc.w = fmaf(v0.w, w0, acc.w);
        acc.x = fmaf(v1.x, w1, acc.x); acc.y = fmaf(v1.y, w1, acc.y);
        acc.z = fmaf(v1.z, w1, acc.z); acc.w = fmaf(v1.w, w1, acc.w);
        acc.x = fmaf(v2.x, w2, acc.x); acc.y = fmaf(v2.y, w2, acc.y);
        acc.z = fmaf(v2.z, w2, acc.z); acc.w = fmaf(v2.w, w2, acc.w);
        acc.x = fmaf(v3.x, w3, acc.x); acc.y = fmaf(v3.y, w3, acc.y);
        acc.z = fmaf(v3.z, w3, acc.z); acc.w = fmaf(v3.w, w3, acc.w);
    }
    for (; e < end; e++) {
        int s0 = col[e];
        float w0 = dinv[s0] * dn;
        float4 v0 = xw4[(size_t)s0 * 32 + sub];
        acc.x = fmaf(v0.x, w0, acc.x); acc.y = fmaf(v0.y, w0, acc.y);
        acc.z = fmaf(v0.z, w0, acc.z); acc.w = fmaf(v0.w, w0, acc.w);
    }
    float4 b4 = ((const float4*)b)[sub];
    acc.x = fmaxf(acc.x + b4.x, 0.f);
    acc.y = fmaxf(acc.y + b4.y, 0.f);
    acc.z = fmaxf(acc.z + b4.z, 0.f);
    acc.w = fmaxf(acc.w + b4.w, 0.f);
    ((float4*)out)[(size_t)n * 32 + sub] = acc;
}

// ---------------------------------------------------------------- Mamba scan, shuffle-free, float4-staged
// One d-channel per thread; 16 states in registers; B/C/dt LDS reads are broadcasts;
// C-dot in-register (zero cross-lane ops). All staging float4, conflict-free banks.
// chk/init layout is s-major: [chunk][s][d] -> all global I/O coalesced.
__global__ __launch_bounds__(256) void scan_phase1(const float* __restrict__ xst,
                                                   const float* __restrict__ dblt,
                                                   const float* __restrict__ A_log,
                                                   const float* __restrict__ W_dt,
                                                   const float* __restrict__ b_dt,
                                                   float* __restrict__ chkP,
                                                   float* __restrict__ chkH) {
    __shared__ float Tx[CHLEN][257];
    __shared__ float D8s[8][33];
    __shared__ float Bt[CHLEN][20];
    int tid = threadIdx.x;
    int chunk = blockIdx.x;
    int t0 = chunk * CHLEN;
#pragma unroll
    for (int jj = 0; jj < 8; jj++) {
        int lin = tid + jj * 256;
        int dd = lin >> 3, tq = (lin & 7) * 4;
        float4 v = *(const float4*)&xst[(size_t)dd * NN + t0 + tq];
        Tx[tq + 0][dd] = v.x; Tx[tq + 1][dd] = v.y;
        Tx[tq + 2][dd] = v.z; Tx[tq + 3][dd] = v.w;
    }
    if (tid < 128) {          // B rows (dblt rows 8..23) -> Bt[t][s]
        int s = tid >> 3, tq = (tid & 7) * 4;
        float4 v = *(const float4*)&dblt[(size_t)(8 + s) * NN + t0 + tq];
        Bt[tq + 0][s] = v.x; Bt[tq + 1][s] = v.y;
        Bt[tq + 2][s] = v.z; Bt[tq + 3][s] = v.w;
    } else if (tid < 192) {   // dt-proj rows 0..7 -> D8s[s][t]
        int l = tid - 128;
        int s = l >> 3, tq = (l & 7) * 4;
        float4 v = *(const float4*)&dblt[(size_t)s * NN + t0 + tq];
        D8s[s][tq + 0] = v.x; D8s[s][tq + 1] = v.y;
        D8s[s][tq + 2] = v.z; D8s[s][tq + 3] = v.w;
    }
    int d = tid;
    float wv[8];
#pragma unroll
    for (int k = 0; k < 8; k++) wv[k] = W_dt[k * DI + d];
    float bd = b_dt[d];
    float A[16];
#pragma unroll
    for (int q = 0; q < 4; q++) {
        float4 al = *(const float4*)&A_log[d * DS + q * 4];
        A[q * 4 + 0] = -expf(al.x); A[q * 4 + 1] = -expf(al.y);
        A[q * 4 + 2] = -expf(al.z); A[q * 4 + 3] = -expf(al.w);
    }
    float h[16], P[16];
#pragma unroll
    for (int s = 0; s < 16; s++) { h[s] = 0.f; P[s] = 1.f; }
    __syncthreads();
#pragma unroll 4
    for (int t = 0; t < CHLEN; t++) {
        float acc = bd;
#pragma unroll
        for (int k = 0; k < 8; k++) acc = fmaf(D8s[k][t], wv[k], acc);
        float dtv = softplusf(acc);
        float dx = dtv * Tx[t][d];
        float4 b0 = *(const float4*)&Bt[t][0];
        float4 b1 = *(const float4*)&Bt[t][4];
        float4 b2 = *(const float4*)&Bt[t][8];
        float4 b3 = *(const float4*)&Bt[t][12];
        float Bv[16] = {b0.x,b0.y,b0.z,b0.w, b1.x,b1.y,b1.z,b1.w,
                        b2.x,b2.y,b2.z,b2.w, b3.x,b3.y,b3.z,b3.w};
#pragma unroll
        for (int s = 0; s < 16; s++) {
            float a = __expf(dtv * A[s]);
            h[s] = fmaf(a, h[s], dx * Bv[s]);
            P[s] *= a;
        }
    }
    size_t base = (size_t)chunk * 4096 + d;
#pragma unroll
    for (int s = 0; s < 16; s++) {
        chkP[base + s * 256] = P[s];
        chkH[base + s * 256] = h[s];
    }
}

// phase2: serial over 64 groups of 8 chunks with a 4-deep rotating prefetch
// (delta = latency/4). init written IN-PLACE over chkP: writes of group g trail
// reads of group g by 4 groups within the same thread -> safe.
__global__ void scan_phase2(const float* chkP, const float* chkH, float* init) {
    int idx = blockIdx.x * blockDim.x + threadIdx.x;  // 4096 total
    float h = 0.f;
    float p0[8], q0[8], p1[8], q1[8], p2[8], q2[8], p3[8], q3[8];
#pragma unroll
    for (int j = 0; j < 8; j++) {
        p0[j] = chkP[(0 * 8 + j) * 4096 + idx]; q0[j] = chkH[(0 * 8 + j) * 4096 + idx];
        p1[j] = chkP[(1 * 8 + j) * 4096 + idx]; q1[j] = chkH[(1 * 8 + j) * 4096 + idx];
        p2[j] = chkP[(2 * 8 + j) * 4096 + idx]; q2[j] = chkH[(2 * 8 + j) * 4096 + idx];
        p3[j] = chkP[(3 * 8 + j) * 4096 + idx]; q3[j] = chkH[(3 * 8 + j) * 4096 + idx];
    }
    for (int g = 0; g < 64; g += 4) {
#pragma unroll
        for (int j = 0; j < 8; j++) { init[((g + 0) * 8 + j) * 4096 + idx] = h; h = fmaf(p0[j], h, q0[j]); }
        if (g + 4 < 64) {
#pragma unroll
            for (int j = 0; j < 8; j++) { p0[j] = chkP[((g + 4) * 8 + j) * 4096 + idx];
                                          q0[j] = chkH[((g + 4) * 8 + j) * 4096 + idx]; }
        }
#pragma unroll
        for (int j = 0; j < 8; j++) { init[((g + 1) * 8 + j) * 4096 + idx] = h; h = fmaf(p1[j], h, q1[j]); }
        if (g + 5 < 64) {
#pragma unroll
            for (int j = 0; j < 8; j++) { p1[j] = chkP[((g + 5) * 8 + j) * 4096 + idx];
                                          q1[j] = chkH[((g + 5) * 8 + j) * 4096 + idx]; }
        }
#pragma unroll
        for (int j = 0; j < 8; j++) { init[((g + 2) * 8 + j) * 4096 + idx] = h; h = fmaf(p2[j], h, q2[j]); }
        if (g + 6 < 64) {
#pragma unroll
            for (int j = 0; j < 8; j++) { p2[j] = chkP[((g + 6) * 8 + j) * 4096 + idx];
                                          q2[j] = chkH[((g + 6) * 8 + j) * 4096 + idx]; }
        }
#pragma unroll
        for (int j = 0; j < 8; j++) { init[((g + 3) * 8 + j) * 4096 + idx] = h; h = fmaf(p3[j], h, q3[j]); }
        if (g + 7 < 64) {
#pragma unroll
            for (int j = 0; j < 8; j++) { p3[j] = chkP[((g + 7) * 8 + j) * 4096 + idx];
                                          q3[j] = chkH[((g + 7) * 8 + j) * 4096 + idx]; }
        }
    }
}

// phase3: phase1 structure + in-register C-dot; y overwrites Tx in place (element
// [t][d] owned by thread d alone); coalesced float4 epilogue multiplies by silu(z).
__global__ __launch_bounds__(256) void scan_phase3(const float* __restrict__ xst,
                                                   const float* __restrict__ dblt,
                                                   const float* __restrict__ A_log,
                                                   const float* __restrict__ W_dt,
                                                   const float* __restrict__ b_dt,
                                                   const float* __restrict__ init,
                                                   const float* __restrict__ D_p,
                                                   const float* __restrict__ szt,
                                                   float* __restrict__ yt) {
    __shared__ float Tx[CHLEN][257];
    __shared__ float D8s[8][33];
    __shared__ float Bt[CHLEN][20];
    __shared__ float Ctt[CHLEN][20];
    int tid = threadIdx.x;
    int chunk = blockIdx.x;
    int t0 = chunk * CHLEN;
#pragma unroll
    for (int jj = 0; jj < 8; jj++) {
        int lin = tid + jj * 256;
        int dd = lin >> 3, tq = (lin & 7) * 4;
        float4 v = *(const float4*)&xst[(size_t)dd * NN + t0 + tq];
        Tx[tq + 0][dd] = v.x; Tx[tq + 1][dd] = v.y;
        Tx[tq + 2][dd] = v.z; Tx[tq + 3][dd] = v.w;
    }
    if (tid < 128) {          // B rows -> Bt
        int s = tid >> 3, tq = (tid & 7) * 4;
        float4 v = *(const float4*)&dblt[(size_t)(8 + s) * NN + t0 + tq];
        Bt[tq + 0][s] = v.x; Bt[tq + 1][s] = v.y;
        Bt[tq + 2][s] = v.z; Bt[tq + 3][s] = v.w;
    } else {                  // C rows (24..39) -> Ctt
        int l = tid - 128;
        int s = l >> 3, tq = (l & 7) * 4;
        float4 v = *(const float4*)&dblt[(size_t)(24 + s) * NN + t0 + tq];
        Ctt[tq + 0][s] = v.x; Ctt[tq + 1][s] = v.y;
        Ctt[tq + 2][s] = v.z; Ctt[tq + 3][s] = v.w;
    }
    if (tid < 64) {           // dt-proj rows 0..7 -> D8s (second stage for threads 0..63)
        int s = tid >> 3, tq = (tid & 7) * 4;
        float4 v = *(const float4*)&dblt[(size_t)s * NN + t0 + tq];
        D8s[s][tq + 0] = v.x; D8s[s][tq + 1] = v.y;
        D8s[s][tq + 2] = v.z; D8s[s][tq + 3] = v.w;
    }
    int d = tid;
    float wv[8];
#pragma unroll
    for (int k = 0; k < 8; k++) wv[k] = W_dt[k * DI + d];
    float bd = b_dt[d];
    float Dd = D_p[d];
    float A[16];
#pragma unroll
    for (int q = 0; q < 4; q++) {
        float4 al = *(const float4*)&A_log[d * DS + q * 4];
        A[q * 4 + 0] = -expf(al.x); A[q * 4 + 1] = -expf(al.y);
        A[q * 4 + 2] = -expf(al.z); A[q * 4 + 3] = -expf(al.w);
    }
    float h[16];
    size_t ibase = (size_t)chunk * 4096 + d;
#pragma unroll
    for (int s = 0; s < 16; s++) h[s] = init[ibase + s * 256];
    __syncthreads();
#pragma unroll 4
    for (int t = 0; t < CHLEN; t++) {
        float acc = bd;
#pragma unroll
        for (int k = 0; k < 8; k++) acc = fmaf(D8s[k][t], wv[k], acc);
        float dtv = softplusf(acc);
        float x = Tx[t][d];
        float dx = dtv * x;
        float4 b0 = *(const float4*)&Bt[t][0];
        float4 b1 = *(const float4*)&Bt[t][4];
        float4 b2 = *(const float4*)&Bt[t][8];
        float4 b3 = *(const float4*)&Bt[t][12];
        float4 c0 = *(const float4*)&Ctt[t][0];
        float4 c1 = *(const float4*)&Ctt[t][4];
        float4 c2 = *(const float4*)&Ctt[t][8];
        float4 c3 = *(const float4*)&Ctt[t][12];
        float Bv[16] = {b0.x,b0.y,b0.z,b0.w, b1.x,b1.y,b1.z,b1.w,
                        b2.x,b2.y,b2.z,b2.w, b3.x,b3.y,b3.z,b3.w};
        float Cv[16] = {c0.x,c0.y,c0.z,c0.w, c1.x,c1.y,c1.z,c1.w,
                        c2.x,c2.y,c2.z,c2.w, c3.x,c3.y,c3.z,c3.w};
        float y = 0.f;
#pragma unroll
        for (int s = 0; s < 16; s++) {
            float a = __expf(dtv * A[s]);
            h[s] = fmaf(a, h[s], dx * Bv[s]);
            y = fmaf(h[s], Cv[s], y);
        }
        Tx[t][d] = fmaf(Dd, x, y);   // in-place: element owned by this thread only
    }
    __syncthreads();
#pragma unroll
    for (int jj = 0; jj < 8; jj++) {
        int lin = tid + jj * 256;
        int dd = lin >> 3, tq = (lin & 7) * 4;
        float4 sz = *(const float4*)&szt[(size_t)dd * NN + t0 + tq];
        float4 o;
        o.x = Tx[tq + 0][dd] * sz.x;
        o.y = Tx[tq + 1][dd] * sz.y;
        o.z = Tx[tq + 2][dd] * sz.z;
        o.w = Tx[tq + 3][dd] * sz.w;
        *(float4*)&yt[(size_t)dd * NN + t0 + tq] = o;
    }
}

// ---------------------------------------------------------------- output heads (ge_norm folded in)
__global__ void heads_kernel(const float* __restrict__ ge, const int* __restrict__ counts,
                             const float* Wc, const float* bc, const float* Wh, const float* bh,
                             const float* Wt, const float* bt, const float* Wp1, const float* bp1,
                             const float* Wp2, const float* bp2, const float* Wd, const float* bd,
                             const float* Ws, const float* bs, float* __restrict__ out) {
    int col = blockIdx.x * blockDim.x + threadIdx.x;
    int b = blockIdx.y;
    if (col >= OUTW) return;
    const float* W; const float* bi; int lc, w;
    if (col < 1)         { W = Wc;  bi = bc;  lc = col;        w = 1; }
    else if (col < 5)    { W = Wh;  bi = bh;  lc = col - 1;    w = 4; }
    else if (col < 8)    { W = Wt;  bi = bt;  lc = col - 5;    w = 3; }
    else if (col < 520)  { W = Wp1; bi = bp1; lc = col - 8;    w = 512; }
    else if (col < 1032) { W = Wp2; bi = bp2; lc = col - 520;  w = 512; }
    else if (col < 1544) { W = Wd;  bi = bd;  lc = col - 1032; w = 512; }
    else                 { W = Ws;  bi = bs;  lc = col - 1544; w = 8; }
    float scale = 1.f / fmaxf((float)counts[b], 1.f);
    float dot = 0.f;
#pragma unroll 8
    for (int f = 0; f < HH; f++) dot = fmaf(ge[b * HH + f], W[f * w + lc], dot);
    out[(size_t)b * OUTW + col] = bi[lc] + scale * dot;
}

// ---------------------------------------------------------------- launch
extern "C" void kernel_launch(void* const* d_in, const int* in_sizes, int n_in,
                              void* d_out, int out_size, void* d_ws, size_t ws_size,
                              hipStream_t stream) {
    const float* nf      = (const float*)d_in[0];
    const int*   ei      = (const int*)d_in[1];
    const int*   batch   = (const int*)d_in[2];
    const float* W_in    = (const float*)d_in[3];
    const float* b_in    = (const float*)d_in[4];
    const float* W_g1    = (const float*)d_in[5];
    const float* b_g1    = (const float*)d_in[6];
    const float* W_g2    = (const float*)d_in[7];
    const float* b_g2    = (const float*)d_in[8];
    const float* W_inproj= (const float*)d_in[9];
    const float* conv_w  = (const float*)d_in[10];
    const float* conv_b  = (const float*)d_in[11];
    const float* W_xproj = (const float*)d_in[12];
    const float* W_dt    = (const float*)d_in[13];
    const float* b_dt    = (const float*)d_in[14];
    const float* A_log   = (const float*)d_in[15];
    const float* D_p     = (const float*)d_in[16];
    const float* W_out   = (const float*)d_in[17];
    const float* gamma   = (const float*)d_in[18];
    const float* beta    = (const float*)d_in[19];
    const float* Wc = (const float*)d_in[20]; const float* bc = (const float*)d_in[21];
    const float* Wh = (const float*)d_in[22]; const float* bh = (const float*)d_in[23];
    const float* Wt = (const float*)d_in[24]; const float* bt = (const float*)d_in[25];
    const float* Wp1= (const float*)d_in[26]; const float* bp1= (const float*)d_in[27];
    const float* Wp2= (const float*)d_in[28]; const float* bp2= (const float*)d_in[29];
    const float* Wd = (const float*)d_in[30]; const float* bd = (const float*)d_in[31];
    const float* Ws = (const float*)d_in[32]; const float* bs = (const float*)d_in[33];

    const int* e_src = ei;
    const int* e_dst = ei + EE;

    // workspace layout (floats, then ints)
    float* w = (float*)d_ws;
    size_t o = 0;
    float* F0   = w + o; o += (size_t)NN * HH;   // dead during scan -> CHP (512*4096 = NN*HH exactly)
    float* F1   = w + o; o += (size_t)NN * HH;   // dead during scan -> CHH
    float* F2   = w + o; o += (size_t)NN * HH;
    float* XZT  = w + o; o += (size_t)NN * 512;  // xz TRANSPOSED [512][NN]; dead after conv:
    float* YT   = XZT;                            //   y^T [DI][NN]
    float* XST  = w + o; o += (size_t)NN * DI;   // x (conv+silu), transposed [DI][NN]
    float* SZT  = w + o; o += (size_t)NN * DI;   // silu(z), transposed [DI][NN]
    float* DBLT = w + o; o += (size_t)NN * 40;   // [40][NN]; 0..7 = dt-proj^T, 8..23 = B^T, 24..39 = C^T
    float* GE   = w + o; o += BB * HH;
    float* DINV = w + o; o += NN;
    int* ip = (int*)(w + o);
    int* CNT    = ip; ip += NN;
    int* ROWPTR = ip; ip += NN + 1;
    int* CURSOR = ip; ip += NN;
    int* COL    = ip; ip += EE;
    int* COUNTS = ip; ip += BB;

    // overlays (regions dead during the scan)
    float* CHP  = F0;                         // NCH*4096 = 2M floats (== F0 exactly)
    float* CHH  = F1;                         // 2M floats
    float* INI  = CHP;                        // init written in-place over chkP (phase2)

    // zero scratch (single kernel instead of 3 memsets)
    zero_kernel<<<(NN + 255) / 256, 256, 0, stream>>>(CNT, GE, COUNTS);

    // CSR build
    deg_kernel<<<EE / 256, 256, 0, stream>>>(e_dst, CNT);
    prefix_kernel<<<1, 1024, 0, stream>>>(CNT, ROWPTR, CURSOR, DINV);
    scatter_kernel<<<EE / 256, 256, 0, stream>>>(e_src, e_dst, CURSOR, COL);

    // xw1 = relu(nf @ W_in + b_in) @ W_g1  (h0 never materialized)
    gemm_in_g1<<<dim3(2, NN / 64), 256, 0, stream>>>(nf, W_in, b_in, W_g1, F1);
    gcn_gather4<<<NN / 8, 256, 0, stream>>>(F1, ROWPTR, COL, DINV, b_g1, F0);
    // GCN layer 2
    gemm_k<<<dim3(2, NN / 64), 256, 0, stream>>>(F0, W_g2, nullptr, F1, NN, HH, HH, 0);
    gcn_gather4<<<NN / 8, 256, 0, stream>>>(F1, ROWPTR, COL, DINV, b_g2, F2);  // F2 = h_gnn

    // xz^T = (h_gnn @ W_inproj)^T  (transposed store: all consumers want [512][NN])
    gemm_big512_t<<<dim3(4, NN / 128), 512, 0, stream>>>(F2, W_inproj, XZT, NN, 512, HH);
    // conv + silu over contiguous rows -> XST; silu(z) -> SZT (pure streaming, no LDS)
    conv_silu_rows<<<dim3(NN / 1024, 512), 256, 0, stream>>>(XZT, conv_w, conv_b, XST, SZT);
    // dbl = xs @ W_xproj, written directly transposed -> DBLT (fused)
    gemm_at_dblt<<<NN / 64, 256, 0, stream>>>(XST, W_xproj, DBLT);

    // Mamba scan, shuffle-free: one d per thread, 16 states in registers, float4 staging
    scan_phase1<<<NCH, 256, 0, stream>>>(XST, DBLT, A_log, W_dt, b_dt, CHP, CHH);
    scan_phase2<<<16, 256, 0, stream>>>(CHP, CHH, INI);
    scan_phase3<<<NCH, 256, 0, stream>>>(XST, DBLT, A_log, W_dt, b_dt, INI, D_p, SZT, YT);

    // h_mamba = y @ W_out; + h_gnn; LayerNorm; pooled directly into GE (h_final never stored)
    gemm_at_ln_pool<<<NN / 32, 256, 0, stream>>>(YT, W_out, F2, gamma, beta, batch, GE, COUNTS);

    // heads (ge_norm folded in)
    heads_kernel<<<dim3((OUTW + 127) / 128, BB), 128, 0, stream>>>(
        GE, COUNTS, Wc, bc, Wh, bh, Wt, bt, Wp1, bp1, Wp2, bp2, Wd, bd, Ws, bs, (float*)d_out);
}

// Round 8
// 386.399 us; speedup vs baseline: 1.0841x; 1.0305x over previous
//
#include <hip/hip_runtime.h>
#include <math.h>

#define NN 16384
#define EE 262144
#define FF 32
#define HH 128
#define BB 16
#define DI 256
#define DS 16
#define DC 4
#define DTR 8
#define OUTW 1552
#define NCH 512
#define CHLEN 32    // NCH*CHLEN == NN

// ---------------------------------------------------------------- utilities
__device__ __forceinline__ float siluf(float v) { return v / (1.f + __expf(-v)); }
__device__ __forceinline__ float softplusf(float v) {
    return fmaxf(v, 0.f) + __logf(1.f + __expf(-fabsf(v)));
}
__device__ __forceinline__ unsigned short f2bf(float f) {   // RNE fp32->bf16
    unsigned int u = __float_as_uint(f);
    unsigned int r = (u + 0x7FFFu + ((u >> 16) & 1u)) >> 16;
    return (unsigned short)r;
}
__device__ __forceinline__ float bf2f(unsigned short b) {
    return __uint_as_float(((unsigned int)b) << 16);
}

// ---------------------------------------------------------------- zero scratch (replaces 3 memsets)
__global__ void zero_kernel(int* __restrict__ cnt, float* __restrict__ ge,
                            int* __restrict__ counts) {
    int idx = blockIdx.x * blockDim.x + threadIdx.x;
    if (idx < NN) cnt[idx] = 0;
    if (idx < BB * HH) ge[idx] = 0.f;
    if (idx < BB) counts[idx] = 0;
}

// ---------------------------------------------------------------- CSR build
__global__ void deg_kernel(const int* __restrict__ dst, int* __restrict__ cnt) {
    int e = blockIdx.x * blockDim.x + threadIdx.x;
    if (e < EE) atomicAdd(&cnt[dst[e]], 1);
}

__global__ __launch_bounds__(1024) void prefix_kernel(const int* __restrict__ cnt,
                                                      int* __restrict__ rowptr,
                                                      int* __restrict__ cursor,
                                                      float* __restrict__ dinv) {
    __shared__ int part[1024];
    int tid = threadIdx.x;
    int4 c4[4];
#pragma unroll
    for (int j = 0; j < 4; j++) c4[j] = ((const int4*)cnt)[tid * 4 + j];
    int v[16] = {c4[0].x, c4[0].y, c4[0].z, c4[0].w, c4[1].x, c4[1].y, c4[1].z, c4[1].w,
                 c4[2].x, c4[2].y, c4[2].z, c4[2].w, c4[3].x, c4[3].y, c4[3].z, c4[3].w};
    int s = 0;
#pragma unroll
    for (int j = 0; j < 16; j++) s += v[j];
    part[tid] = s;
    __syncthreads();
    for (int off = 1; off < 1024; off <<= 1) {
        int t = (tid >= off) ? part[tid - off] : 0;
        __syncthreads();
        part[tid] += t;
        __syncthreads();
    }
    int running = part[tid] - s;
    int rp[16];
    float dv[16];
#pragma unroll
    for (int j = 0; j < 16; j++) {
        rp[j] = running;
        running += v[j];
        dv[j] = rsqrtf((float)(v[j] + 1));  // +1 self loop
    }
#pragma unroll
    for (int j = 0; j < 4; j++) {
        int4 r4; r4.x = rp[j*4]; r4.y = rp[j*4+1]; r4.z = rp[j*4+2]; r4.w = rp[j*4+3];
        ((int4*)rowptr)[tid * 4 + j] = r4;
        ((int4*)cursor)[tid * 4 + j] = r4;
        float4 d4; d4.x = dv[j*4]; d4.y = dv[j*4+1]; d4.z = dv[j*4+2]; d4.w = dv[j*4+3];
        ((float4*)dinv)[tid * 4 + j] = d4;
    }
    if (tid == 1023) rowptr[NN] = part[1023];
}

__global__ void scatter_kernel(const int* __restrict__ src, const int* __restrict__ dst,
                               int* __restrict__ cursor, int* __restrict__ col) {
    int e = blockIdx.x * blockDim.x + threadIdx.x;
    if (e < EE) {
        int d = dst[e];
        int pos = atomicAdd(&cursor[d], 1);
        col[pos] = src[e];
    }
}

// ---------------------------------------------------------------- GEMM (fp32 acc, bf16 output)
__global__ __launch_bounds__(256) void gemm_k_bf16(const float* __restrict__ A,
                                                   const float* __restrict__ B,
                                                   unsigned short* __restrict__ C16,
                                                   int M, int Nn, int K) {
    __shared__ float As[16][68];
    __shared__ float Bs[16][68];
    int tid = threadIdx.x;
    int m0 = blockIdx.y * 64;
    int n0 = blockIdx.x * 64;
    int ty = tid >> 4, tx = tid & 15;
    float acc[4][4] = {{0.f}};
    for (int k0 = 0; k0 < K; k0 += 16) {
#pragma unroll
        for (int l = 0; l < 4; l++) {
            int idx = tid + l * 256;
            int i = idx >> 4, j = idx & 15;
            As[j][i] = A[(size_t)(m0 + i) * K + k0 + j];
        }
#pragma unroll
        for (int l = 0; l < 4; l++) {
            int idx = tid + l * 256;
            int i = idx >> 6, j = idx & 63;
            int n = n0 + j;
            Bs[i][j] = (n < Nn) ? B[(size_t)(k0 + i) * Nn + n] : 0.f;
        }
        __syncthreads();
#pragma unroll
        for (int kk = 0; kk < 16; kk++) {
            float4 a4 = *(const float4*)&As[kk][ty * 4];
            float4 b4 = *(const float4*)&Bs[kk][tx * 4];
            float av[4] = {a4.x, a4.y, a4.z, a4.w};
            float bv[4] = {b4.x, b4.y, b4.z, b4.w};
#pragma unroll
            for (int r = 0; r < 4; r++)
#pragma unroll
                for (int c = 0; c < 4; c++) acc[r][c] = fmaf(av[r], bv[c], acc[r][c]);
        }
        __syncthreads();
    }
    int nb = n0 + tx * 4;
    if (nb < Nn) {
#pragma unroll
        for (int r = 0; r < 4; r++) {
            int m = m0 + ty * 4 + r;
            ushort4 v;
            v.x = f2bf(acc[r][0]); v.y = f2bf(acc[r][1]);
            v.z = f2bf(acc[r][2]); v.w = f2bf(acc[r][3]);
            *(ushort4*)&C16[(size_t)m * Nn + nb] = v;
        }
    }
}

// ---------------------------------------------------------------- fused relu(nf@W_in+b) @ W_g1, bf16 out
union SMemIn {
    struct { float Ns[64][33]; float Ws[32][132]; } s1;   // step-1 staging
    float Bs[16][68];                                     // step-2 W_g1 chunk
};

__global__ __launch_bounds__(256) void gemm_in_g1(const float* __restrict__ nf,
                                                  const float* __restrict__ W_in,
                                                  const float* __restrict__ b_in,
                                                  const float* __restrict__ W_g1,
                                                  unsigned short* __restrict__ out16) {
    __shared__ SMemIn sm;
    __shared__ float Hs[128][68];   // h^T: Hs[k][m]
    int tid = threadIdx.x;
    int m0 = blockIdx.y * 64;
    int n0 = blockIdx.x * 64;
    int ty = tid >> 4, tx = tid & 15;
#pragma unroll
    for (int l = 0; l < 2; l++) {
        int q = tid + l * 256;
        int r = q >> 3, c4 = (q & 7) * 4;
        *(float4*)&sm.s1.Ns[r][c4] = *(const float4*)&nf[(size_t)(m0 + r) * FF + c4];
    }
#pragma unroll
    for (int l = 0; l < 4; l++) {
        int q = tid + l * 256;
        int r = q >> 5, c4 = (q & 31) * 4;
        *(float4*)&sm.s1.Ws[r][c4] = *(const float4*)&W_in[(size_t)r * HH + c4];
    }
    __syncthreads();
    {
        float4 b0 = *(const float4*)&b_in[tx * 4];
        float4 b1 = *(const float4*)&b_in[64 + tx * 4];
        float hacc[4][8];
#pragma unroll
        for (int r = 0; r < 4; r++) {
            hacc[r][0] = b0.x; hacc[r][1] = b0.y; hacc[r][2] = b0.z; hacc[r][3] = b0.w;
            hacc[r][4] = b1.x; hacc[r][5] = b1.y; hacc[r][6] = b1.z; hacc[r][7] = b1.w;
        }
#pragma unroll
        for (int k = 0; k < FF; k++) {
            float av[4];
#pragma unroll
            for (int r = 0; r < 4; r++) av[r] = sm.s1.Ns[ty * 4 + r][k];
            float wv[8];
#pragma unroll
            for (int c = 0; c < 4; c++) {
                wv[c]     = sm.s1.Ws[k][tx * 4 + c];
                wv[c + 4] = sm.s1.Ws[k][64 + tx * 4 + c];
            }
#pragma unroll
            for (int r = 0; r < 4; r++)
#pragma unroll
                for (int c = 0; c < 8; c++) hacc[r][c] = fmaf(av[r], wv[c], hacc[r][c]);
        }
#pragma unroll
        for (int r = 0; r < 4; r++)
#pragma unroll
            for (int c = 0; c < 4; c++) {
                Hs[tx * 4 + c][ty * 4 + r]      = fmaxf(hacc[r][c], 0.f);
                Hs[64 + tx * 4 + c][ty * 4 + r] = fmaxf(hacc[r][c + 4], 0.f);
            }
    }
    __syncthreads();
    float acc[4][4] = {{0.f}};
    for (int k0 = 0; k0 < HH; k0 += 16) {
        *(float4*)&sm.Bs[tid >> 4][(tid & 15) * 4] =
            *(const float4*)&W_g1[(size_t)(k0 + (tid >> 4)) * HH + n0 + (tid & 15) * 4];
        __syncthreads();
#pragma unroll
        for (int kk = 0; kk < 16; kk++) {
            float4 a4 = *(const float4*)&Hs[k0 + kk][ty * 4];
            float4 b4 = *(const float4*)&sm.Bs[kk][tx * 4];
            float av[4] = {a4.x, a4.y, a4.z, a4.w};
            float bv[4] = {b4.x, b4.y, b4.z, b4.w};
#pragma unroll
            for (int r = 0; r < 4; r++)
#pragma unroll
                for (int c = 0; c < 4; c++) acc[r][c] = fmaf(av[r], bv[c], acc[r][c]);
        }
        __syncthreads();
    }
#pragma unroll
    for (int r = 0; r < 4; r++) {
        int m = m0 + ty * 4 + r;
        ushort4 v;
        v.x = f2bf(acc[r][0]); v.y = f2bf(acc[r][1]);
        v.z = f2bf(acc[r][2]); v.w = f2bf(acc[r][3]);
        *(ushort4*)&out16[(size_t)m * HH + n0 + tx * 4] = v;
    }
}

// ---------------------------------------------------------------- big-tile GEMM, 512 threads, TRANSPOSED output
__global__ __launch_bounds__(512, 4) void gemm_big512_t(const float* __restrict__ A,
                                                        const float* __restrict__ B,
                                                        float* __restrict__ CT,
                                                        int M, int Nn, int K) {
    __shared__ float As[16][132];
    __shared__ float Bs[16][132];
    int tid = threadIdx.x;
    int m0 = blockIdx.y * 128;
    int n0 = blockIdx.x * 128;
    int ty = tid >> 4;          // 0..31 -> m rows ty*4..ty*4+3
    int tx = tid & 15;          // n cols tx*4 and 64+tx*4
    float acc[4][8] = {{0.f}};
    for (int k0 = 0; k0 < K; k0 += 16) {
        {   // A: 128 m x 16 k, one float4 per thread -> As[k][m]
            int m = tid >> 2;
            int kc = (tid & 3) * 4;
            float4 a = *(const float4*)&A[(size_t)(m0 + m) * K + k0 + kc];
            As[kc + 0][m] = a.x; As[kc + 1][m] = a.y;
            As[kc + 2][m] = a.z; As[kc + 3][m] = a.w;
        }
        {   // B: 16 k x 128 n, one float4 per thread
            int krow = tid >> 5;
            int c4 = (tid & 31) * 4;
            *(float4*)&Bs[krow][c4] = *(const float4*)&B[(size_t)(k0 + krow) * Nn + n0 + c4];
        }
        __syncthreads();
#pragma unroll
        for (int kk = 0; kk < 16; kk++) {
            float4 a4 = *(const float4*)&As[kk][ty * 4];
            float4 b0 = *(const float4*)&Bs[kk][tx * 4];
            float4 b1 = *(const float4*)&Bs[kk][64 + tx * 4];
            float av[4] = {a4.x, a4.y, a4.z, a4.w};
            float bv[8] = {b0.x, b0.y, b0.z, b0.w, b1.x, b1.y, b1.z, b1.w};
#pragma unroll
            for (int r = 0; r < 4; r++)
#pragma unroll
                for (int c = 0; c < 8; c++) acc[r][c] = fmaf(av[r], bv[c], acc[r][c]);
        }
        __syncthreads();
    }
    // transposed store: CT[n][m]
#pragma unroll
    for (int cc = 0; cc < 4; cc++) {
        float4 v;
        v.x = acc[0][cc]; v.y = acc[1][cc]; v.z = acc[2][cc]; v.w = acc[3][cc];
        *(float4*)&CT[(size_t)(n0 + tx * 4 + cc) * NN + m0 + ty * 4] = v;
        float4 u;
        u.x = acc[0][cc + 4]; u.y = acc[1][cc + 4]; u.z = acc[2][cc + 4]; u.w = acc[3][cc + 4];
        *(float4*)&CT[(size_t)(n0 + 64 + tx * 4 + cc) * NN + m0 + ty * 4] = u;
    }
}

// ---------------------------------------------------------------- conv + silu over transposed xz
__global__ __launch_bounds__(256) void conv_silu_rows(const float* __restrict__ xzt,
                                                      const float* __restrict__ cw,
                                                      const float* __restrict__ cb,
                                                      float* __restrict__ xst,
                                                      float* __restrict__ szt) {
    int d = blockIdx.y;                       // 0..511 (x rows then z rows)
    int tg = blockIdx.x * 1024 + threadIdx.x * 4;
    const float* row = xzt + (size_t)d * NN;
    float4 cur = *(const float4*)&row[tg];
    if (d < DI) {
        float4 prev;
        if (tg == 0) { prev.x = 0.f; prev.y = 0.f; prev.z = 0.f; prev.w = 0.f; }
        else prev = *(const float4*)&row[tg - 4];
        float w0 = cw[d * DC + 0], w1 = cw[d * DC + 1];
        float w2 = cw[d * DC + 2], w3 = cw[d * DC + 3];
        float b = cb[d];
        float4 o;
        o.x = siluf(b + w0 * prev.y + w1 * prev.z + w2 * prev.w + w3 * cur.x);
        o.y = siluf(b + w0 * prev.z + w1 * prev.w + w2 * cur.x + w3 * cur.y);
        o.z = siluf(b + w0 * prev.w + w1 * cur.x + w2 * cur.y + w3 * cur.z);
        o.w = siluf(b + w0 * cur.x + w1 * cur.y + w2 * cur.z + w3 * cur.w);
        *(float4*)&xst[(size_t)d * NN + tg] = o;
    } else {
        float4 o;
        o.x = siluf(cur.x); o.y = siluf(cur.y); o.z = siluf(cur.z); o.w = siluf(cur.w);
        *(float4*)&szt[(size_t)(d - DI) * NN + tg] = o;
    }
}

// ---------------------------------------------------------------- xproj GEMM (A^T) + transposed output
__global__ __launch_bounds__(256) void gemm_at_dblt(const float* __restrict__ AT,
                                                    const float* __restrict__ B,
                                                    float* __restrict__ dblt) {
    __shared__ float As[16][68];
    __shared__ float Bs[16][68];
    __shared__ float Ct[64][41];
    int tid = threadIdx.x;
    int m0 = blockIdx.x * 64;
    int ty = tid >> 4, tx = tid & 15;
    float acc[4][4] = {{0.f}};
    for (int k0 = 0; k0 < DI; k0 += 16) {
#pragma unroll
        for (int l = 0; l < 4; l++) {
            int idx = tid + l * 256;
            int kk = idx >> 6, i = idx & 63;
            As[kk][i] = AT[(size_t)(k0 + kk) * NN + m0 + i];
        }
#pragma unroll
        for (int l = 0; l < 4; l++) {
            int idx = tid + l * 256;
            int i = idx >> 6, j = idx & 63;
            Bs[i][j] = (j < 40) ? B[(size_t)(k0 + i) * 40 + j] : 0.f;
        }
        __syncthreads();
#pragma unroll
        for (int kk = 0; kk < 16; kk++) {
            float4 a4 = *(const float4*)&As[kk][ty * 4];
            float4 b4 = *(const float4*)&Bs[kk][tx * 4];
            float av[4] = {a4.x, a4.y, a4.z, a4.w};
            float bv[4] = {b4.x, b4.y, b4.z, b4.w};
#pragma unroll
            for (int r = 0; r < 4; r++)
#pragma unroll
                for (int c = 0; c < 4; c++) acc[r][c] = fmaf(av[r], bv[c], acc[r][c]);
        }
        __syncthreads();
    }
    if (tx * 4 < 40) {
#pragma unroll
        for (int r = 0; r < 4; r++) {
            int m = ty * 4 + r;
            Ct[m][tx * 4 + 0] = acc[r][0];
            Ct[m][tx * 4 + 1] = acc[r][1];
            Ct[m][tx * 4 + 2] = acc[r][2];
            Ct[m][tx * 4 + 3] = acc[r][3];
        }
    }
    __syncthreads();
#pragma unroll
    for (int l = 0; l < 10; l++) {
        int idx = tid + l * 256;
        int n = idx >> 6, m = idx & 63;
        dblt[(size_t)n * NN + m0 + m] = Ct[m][n];
    }
}

// ---------------------------------------------------------------- fused W_out GEMM + add + LayerNorm + POOL
__global__ __launch_bounds__(256) void gemm_at_ln_pool(const float* __restrict__ AT,
                                                       const float* __restrict__ B,
                                                       const float* __restrict__ hg,
                                                       const float* __restrict__ gamma,
                                                       const float* __restrict__ beta,
                                                       const int* __restrict__ batch,
                                                       float* __restrict__ ge,
                                                       int* __restrict__ counts) {
    __shared__ float As[16][36];
    __shared__ float Bs[16][132];
    __shared__ float lnb[32][132];
    __shared__ int gb[32];
    int tid = threadIdx.x;
    int m0 = blockIdx.x * 32;
    int ty = tid >> 4, tx = tid & 15;
    float acc[2][8] = {{0.f}};
    for (int k0 = 0; k0 < 256; k0 += 16) {
        {
            int idx = tid * 2;
            int kk = idx >> 5, i = idx & 31;
            As[kk][i] = AT[(size_t)(k0 + kk) * NN + m0 + i];
            As[kk][i + 1] = AT[(size_t)(k0 + kk) * NN + m0 + i + 1];
        }
        {
            int krow = tid >> 4;
            int c8 = (tid & 15) * 8;
            const float* bp = &B[(size_t)(k0 + krow) * HH + c8];
            *(float4*)&Bs[krow][c8] = *(const float4*)bp;
            *(float4*)&Bs[krow][c8 + 4] = *(const float4*)(bp + 4);
        }
        __syncthreads();
#pragma unroll
        for (int kk = 0; kk < 16; kk++) {
            float a0 = As[kk][ty * 2];
            float a1 = As[kk][ty * 2 + 1];
            float4 b0 = *(const float4*)&Bs[kk][tx * 4];
            float4 b1 = *(const float4*)&Bs[kk][64 + tx * 4];
            float bv[8] = {b0.x, b0.y, b0.z, b0.w, b1.x, b1.y, b1.z, b1.w};
#pragma unroll
            for (int c = 0; c < 8; c++) {
                acc[0][c] = fmaf(a0, bv[c], acc[0][c]);
                acc[1][c] = fmaf(a1, bv[c], acc[1][c]);
            }
        }
        __syncthreads();
    }
    if (tid < 32) gb[tid] = batch[m0 + tid];
    float4 g0 = *(const float4*)&gamma[tx * 4];
    float4 g1 = *(const float4*)&gamma[64 + tx * 4];
    float4 be0 = *(const float4*)&beta[tx * 4];
    float4 be1 = *(const float4*)&beta[64 + tx * 4];
    float gv[8] = {g0.x, g0.y, g0.z, g0.w, g1.x, g1.y, g1.z, g1.w};
    float bv[8] = {be0.x, be0.y, be0.z, be0.w, be1.x, be1.y, be1.z, be1.w};
#pragma unroll
    for (int r = 0; r < 2; r++) {
        int m = m0 + ty * 2 + r;
        float4 h0 = *(const float4*)&hg[(size_t)m * HH + tx * 4];
        float4 h1 = *(const float4*)&hg[(size_t)m * HH + 64 + tx * 4];
        float v[8] = {acc[r][0] + h0.x, acc[r][1] + h0.y, acc[r][2] + h0.z, acc[r][3] + h0.w,
                      acc[r][4] + h1.x, acc[r][5] + h1.y, acc[r][6] + h1.z, acc[r][7] + h1.w};
        float sum = 0.f;
#pragma unroll
        for (int c = 0; c < 8; c++) sum += v[c];
        sum += __shfl_xor(sum, 1); sum += __shfl_xor(sum, 2);
        sum += __shfl_xor(sum, 4); sum += __shfl_xor(sum, 8);
        float mu = sum * (1.f / 128.f);
        float vs = 0.f;
#pragma unroll
        for (int c = 0; c < 8; c++) { float dd = v[c] - mu; vs += dd * dd; }
        vs += __shfl_xor(vs, 1); vs += __shfl_xor(vs, 2);
        vs += __shfl_xor(vs, 4); vs += __shfl_xor(vs, 8);
        float inv = rsqrtf(vs * (1.f / 128.f) + 1e-5f);
        int lr = ty * 2 + r;
        float4 o0, o1;
        o0.x = (v[0] - mu) * inv * gv[0] + bv[0];
        o0.y = (v[1] - mu) * inv * gv[1] + bv[1];
        o0.z = (v[2] - mu) * inv * gv[2] + bv[2];
        o0.w = (v[3] - mu) * inv * gv[3] + bv[3];
        o1.x = (v[4] - mu) * inv * gv[4] + bv[4];
        o1.y = (v[5] - mu) * inv * gv[5] + bv[5];
        o1.z = (v[6] - mu) * inv * gv[6] + bv[6];
        o1.w = (v[7] - mu) * inv * gv[7] + bv[7];
        *(float4*)&lnb[lr][tx * 4] = o0;
        *(float4*)&lnb[lr][64 + tx * 4] = o1;
    }
    __syncthreads();
    if (tid < HH) {
        int f = tid;
        int gcur = gb[0];
        float acc2 = 0.f;
        int cnt = 0;
#pragma unroll 4
        for (int i = 0; i < 32; i++) {
            int g = gb[i];
            if (g != gcur) {
                atomicAdd(&ge[gcur * HH + f], acc2);
                if (f == 0) atomicAdd(&counts[gcur], cnt);
                acc2 = 0.f; cnt = 0; gcur = g;
            }
            acc2 += lnb[i][f];
            cnt++;
        }
        atomicAdd(&ge[gcur * HH + f], acc2);
        if (f == 0) atomicAdd(&counts[gcur], cnt);
    }
}

// ---------------------------------------------------------------- GCN gather, bf16 operand, 4-edge unroll
__global__ __launch_bounds__(256) void gcn_gather4(const unsigned short* __restrict__ xw,
                                                   const int* __restrict__ rowptr,
                                                   const int* __restrict__ col,
                                                   const float* __restrict__ dinv,
                                                   const float* __restrict__ b,
                                                   float* __restrict__ out) {
    int tid = threadIdx.x;
    int sub = tid & 31;
    int n = blockIdx.x * 8 + (tid >> 5);
    float dn = dinv[n];
    const ushort4* xw4 = (const ushort4*)xw;   // 32 ushort4 per 128-wide row
    ushort4 a = xw4[(size_t)n * 32 + sub];
    float ws = dn * dn;
    float4 acc;
    acc.x = bf2f(a.x) * ws; acc.y = bf2f(a.y) * ws;
    acc.z = bf2f(a.z) * ws; acc.w = bf2f(a.w) * ws;
    int beg = rowptr[n], end = rowptr[n + 1];
    int e = beg;
    for (; e + 4 <= end; e += 4) {
        int s0 = col[e], s1 = col[e + 1], s2 = col[e + 2], s3 = col[e + 3];
        float w0 = dinv[s0] * dn, w1 = dinv[s1] * dn;
        float w2 = dinv[s2] * dn, w3 = dinv[s3] * dn;
        ushort4 v0 = xw4[(size_t)s0 * 32 + sub];
        ushort4 v1 = xw4[(size_t)s1 * 32 + sub];
        ushort4 v2 = xw4[(size_t)s2 * 32 + sub];
        ushort4 v3 = xw4[(size_t)s3 * 32 + sub];
        acc.x = fmaf(bf2f(v0.x), w0, acc.x); acc.y = fmaf(bf2f(v0.y), w0, acc.y);
        acc.z = fmaf(bf2f(v0.z), w0, acc.z); acc.w = fmaf(bf2f(v0.w), w0, acc.w);
        acc.x = fmaf(bf2f(v1.x), w1, acc.x); acc.y = fmaf(bf2f(v1.y), w1, acc.y);
        acc.z = fmaf(bf2f(v1.z), w1, acc.z); acc.w = fmaf(bf2f(v1.w), w1, acc.w);
        acc.x = fmaf(bf2f(v2.x), w2, acc.x); acc.y = fmaf(bf2f(v2.y), w2, acc.y);
        acc.z = fmaf(bf2f(v2.z), w2, acc.z); acc.w = fmaf(bf2f(v2.w), w2, acc.w);
        acc.x = fmaf(bf2f(v3.x), w3, acc.x); acc.y = fmaf(bf2f(v3.y), w3, acc.y);
        acc.z = fmaf(bf2f(v3.z), w3, acc.z); acc.w = fmaf(bf2f(v3.w), w3, acc.w);
    }
    for (; e < end; e++) {
        int s0 = col[e];
        float w0 = dinv[s0] * dn;
        ushort4 v0 = xw4[(size_t)s0 * 32 + sub];
        acc.x = fmaf(bf2f(v0.x), w0, acc.x); acc.y = fmaf(bf2f(v0.y), w0, acc.y);
        acc.z = fmaf(bf2f(v0.z), w0, acc.z); acc.w = fmaf(bf2f(v0.w), w0, acc.w);
    }
    float4 b4 = ((const float4*)b)[sub];
    acc.x = fmaxf(acc.x + b4.x, 0.f);
    acc.y = fmaxf(acc.y + b4.y, 0.f);
    acc.z = fmaxf(acc.z + b4.z, 0.f);
    acc.w = fmaxf(acc.w + b4.w, 0.f);
    ((float4*)out)[(size_t)n * 32 + sub] = acc;
}

// ---------------------------------------------------------------- Mamba scan, shuffle-free, float4-staged
__global__ __launch_bounds__(256) void scan_phase1(const float* __restrict__ xst,
                                                   const float* __restrict__ dblt,
                                                   const float* __restrict__ A_log,
                                                   const float* __restrict__ W_dt,
                                                   const float* __restrict__ b_dt,
                                                   float* __restrict__ chkP,
                                                   float* __restrict__ chkH) {
    __shared__ float Tx[CHLEN][257];
    __shared__ float D8s[8][33];
    __shared__ float Bt[CHLEN][20];
    int tid = threadIdx.x;
    int chunk = blockIdx.x;
    int t0 = chunk * CHLEN;
#pragma unroll
    for (int jj = 0; jj < 8; jj++) {
        int lin = tid + jj * 256;
        int dd = lin >> 3, tq = (lin & 7) * 4;
        float4 v = *(const float4*)&xst[(size_t)dd * NN + t0 + tq];
        Tx[tq + 0][dd] = v.x; Tx[tq + 1][dd] = v.y;
        Tx[tq + 2][dd] = v.z; Tx[tq + 3][dd] = v.w;
    }
    if (tid < 128) {          // B rows (dblt rows 8..23) -> Bt[t][s]
        int s = tid >> 3, tq = (tid & 7) * 4;
        float4 v = *(const float4*)&dblt[(size_t)(8 + s) * NN + t0 + tq];
        Bt[tq + 0][s] = v.x; Bt[tq + 1][s] = v.y;
        Bt[tq + 2][s] = v.z; Bt[tq + 3][s] = v.w;
    } else if (tid < 192) {   // dt-proj rows 0..7 -> D8s[s][t]
        int l = tid - 128;
        int s = l >> 3, tq = (l & 7) * 4;
        float4 v = *(const float4*)&dblt[(size_t)s * NN + t0 + tq];
        D8s[s][tq + 0] = v.x; D8s[s][tq + 1] = v.y;
        D8s[s][tq + 2] = v.z; D8s[s][tq + 3] = v.w;
    }
    int d = tid;
    float wv[8];
#pragma unroll
    for (int k = 0; k < 8; k++) wv[k] = W_dt[k * DI + d];
    float bd = b_dt[d];
    float A[16];
#pragma unroll
    for (int q = 0; q < 4; q++) {
        float4 al = *(const float4*)&A_log[d * DS + q * 4];
        A[q * 4 + 0] = -expf(al.x); A[q * 4 + 1] = -expf(al.y);
        A[q * 4 + 2] = -expf(al.z); A[q * 4 + 3] = -expf(al.w);
    }
    float h[16], P[16];
#pragma unroll
    for (int s = 0; s < 16; s++) { h[s] = 0.f; P[s] = 1.f; }
    __syncthreads();
#pragma unroll 4
    for (int t = 0; t < CHLEN; t++) {
        float acc = bd;
#pragma unroll
        for (int k = 0; k < 8; k++) acc = fmaf(D8s[k][t], wv[k], acc);
        float dtv = softplusf(acc);
        float dx = dtv * Tx[t][d];
        float4 b0 = *(const float4*)&Bt[t][0];
        float4 b1 = *(const float4*)&Bt[t][4];
        float4 b2 = *(const float4*)&Bt[t][8];
        float4 b3 = *(const float4*)&Bt[t][12];
        float Bv[16] = {b0.x,b0.y,b0.z,b0.w, b1.x,b1.y,b1.z,b1.w,
                        b2.x,b2.y,b2.z,b2.w, b3.x,b3.y,b3.z,b3.w};
#pragma unroll
        for (int s = 0; s < 16; s++) {
            float a = __expf(dtv * A[s]);
            h[s] = fmaf(a, h[s], dx * Bv[s]);
            P[s] *= a;
        }
    }
    size_t base = (size_t)chunk * 4096 + d;
#pragma unroll
    for (int s = 0; s < 16; s++) {
        chkP[base + s * 256] = P[s];
        chkH[base + s * 256] = h[s];
    }
}

// phase2: serial over 64 groups of 8 chunks with a 4-deep rotating prefetch.
__global__ void scan_phase2(const float* chkP, const float* chkH, float* init) {
    int idx = blockIdx.x * blockDim.x + threadIdx.x;  // 4096 total
    float h = 0.f;
    float p0[8], q0[8], p1[8], q1[8], p2[8], q2[8], p3[8], q3[8];
#pragma unroll
    for (int j = 0; j < 8; j++) {
        p0[j] = chkP[(0 * 8 + j) * 4096 + idx]; q0[j] = chkH[(0 * 8 + j) * 4096 + idx];
        p1[j] = chkP[(1 * 8 + j) * 4096 + idx]; q1[j] = chkH[(1 * 8 + j) * 4096 + idx];
        p2[j] = chkP[(2 * 8 + j) * 4096 + idx]; q2[j] = chkH[(2 * 8 + j) * 4096 + idx];
        p3[j] = chkP[(3 * 8 + j) * 4096 + idx]; q3[j] = chkH[(3 * 8 + j) * 4096 + idx];
    }
    for (int g = 0; g < 64; g += 4) {
#pragma unroll
        for (int j = 0; j < 8; j++) { init[((g + 0) * 8 + j) * 4096 + idx] = h; h = fmaf(p0[j], h, q0[j]); }
        if (g + 4 < 64) {
#pragma unroll
            for (int j = 0; j < 8; j++) { p0[j] = chkP[((g + 4) * 8 + j) * 4096 + idx];
                                          q0[j] = chkH[((g + 4) * 8 + j) * 4096 + idx]; }
        }
#pragma unroll
        for (int j = 0; j < 8; j++) { init[((g + 1) * 8 + j) * 4096 + idx] = h; h = fmaf(p1[j], h, q1[j]); }
        if (g + 5 < 64) {
#pragma unroll
            for (int j = 0; j < 8; j++) { p1[j] = chkP[((g + 5) * 8 + j) * 4096 + idx];
                                          q1[j] = chkH[((g + 5) * 8 + j) * 4096 + idx]; }
        }
#pragma unroll
        for (int j = 0; j < 8; j++) { init[((g + 2) * 8 + j) * 4096 + idx] = h; h = fmaf(p2[j], h, q2[j]); }
        if (g + 6 < 64) {
#pragma unroll
            for (int j = 0; j < 8; j++) { p2[j] = chkP[((g + 6) * 8 + j) * 4096 + idx];
                                          q2[j] = chkH[((g + 6) * 8 + j) * 4096 + idx]; }
        }
#pragma unroll
        for (int j = 0; j < 8; j++) { init[((g + 3) * 8 + j) * 4096 + idx] = h; h = fmaf(p3[j], h, q3[j]); }
        if (g + 7 < 64) {
#pragma unroll
            for (int j = 0; j < 8; j++) { p3[j] = chkP[((g + 7) * 8 + j) * 4096 + idx];
                                          q3[j] = chkH[((g + 7) * 8 + j) * 4096 + idx]; }
        }
    }
}

// phase3: phase1 structure + in-register C-dot; y overwrites Tx in place.
__global__ __launch_bounds__(256) void scan_phase3(const float* __restrict__ xst,
                                                   const float* __restrict__ dblt,
                                                   const float* __restrict__ A_log,
                                                   const float* __restrict__ W_dt,
                                                   const float* __restrict__ b_dt,
                                                   const float* __restrict__ init,
                                                   const float* __restrict__ D_p,
                                                   const float* __restrict__ szt,
                                                   float* __restrict__ yt) {
    __shared__ float Tx[CHLEN][257];
    __shared__ float D8s[8][33];
    __shared__ float Bt[CHLEN][20];
    __shared__ float Ctt[CHLEN][20];
    int tid = threadIdx.x;
    int chunk = blockIdx.x;
    int t0 = chunk * CHLEN;
#pragma unroll
    for (int jj = 0; jj < 8; jj++) {
        int lin = tid + jj * 256;
        int dd = lin >> 3, tq = (lin & 7) * 4;
        float4 v = *(const float4*)&xst[(size_t)dd * NN + t0 + tq];
        Tx[tq + 0][dd] = v.x; Tx[tq + 1][dd] = v.y;
        Tx[tq + 2][dd] = v.z; Tx[tq + 3][dd] = v.w;
    }
    if (tid < 128) {          // B rows -> Bt
        int s = tid >> 3, tq = (tid & 7) * 4;
        float4 v = *(const float4*)&dblt[(size_t)(8 + s) * NN + t0 + tq];
        Bt[tq + 0][s] = v.x; Bt[tq + 1][s] = v.y;
        Bt[tq + 2][s] = v.z; Bt[tq + 3][s] = v.w;
    } else {                  // C rows (24..39) -> Ctt
        int l = tid - 128;
        int s = l >> 3, tq = (l & 7) * 4;
        float4 v = *(const float4*)&dblt[(size_t)(24 + s) * NN + t0 + tq];
        Ctt[tq + 0][s] = v.x; Ctt[tq + 1][s] = v.y;
        Ctt[tq + 2][s] = v.z; Ctt[tq + 3][s] = v.w;
    }
    if (tid < 64) {           // dt-proj rows 0..7 -> D8s
        int s = tid >> 3, tq = (tid & 7) * 4;
        float4 v = *(const float4*)&dblt[(size_t)s * NN + t0 + tq];
        D8s[s][tq + 0] = v.x; D8s[s][tq + 1] = v.y;
        D8s[s][tq + 2] = v.z; D8s[s][tq + 3] = v.w;
    }
    int d = tid;
    float wv[8];
#pragma unroll
    for (int k = 0; k < 8; k++) wv[k] = W_dt[k * DI + d];
    float bd = b_dt[d];
    float Dd = D_p[d];
    float A[16];
#pragma unroll
    for (int q = 0; q < 4; q++) {
        float4 al = *(const float4*)&A_log[d * DS + q * 4];
        A[q * 4 + 0] = -expf(al.x); A[q * 4 + 1] = -expf(al.y);
        A[q * 4 + 2] = -expf(al.z); A[q * 4 + 3] = -expf(al.w);
    }
    float h[16];
    size_t ibase = (size_t)chunk * 4096 + d;
#pragma unroll
    for (int s = 0; s < 16; s++) h[s] = init[ibase + s * 256];
    __syncthreads();
#pragma unroll 4
    for (int t = 0; t < CHLEN; t++) {
        float acc = bd;
#pragma unroll
        for (int k = 0; k < 8; k++) acc = fmaf(D8s[k][t], wv[k], acc);
        float dtv = softplusf(acc);
        float x = Tx[t][d];
        float dx = dtv * x;
        float4 b0 = *(const float4*)&Bt[t][0];
        float4 b1 = *(const float4*)&Bt[t][4];
        float4 b2 = *(const float4*)&Bt[t][8];
        float4 b3 = *(const float4*)&Bt[t][12];
        float4 c0 = *(const float4*)&Ctt[t][0];
        float4 c1 = *(const float4*)&Ctt[t][4];
        float4 c2 = *(const float4*)&Ctt[t][8];
        float4 c3 = *(const float4*)&Ctt[t][12];
        float Bv[16] = {b0.x,b0.y,b0.z,b0.w, b1.x,b1.y,b1.z,b1.w,
                        b2.x,b2.y,b2.z,b2.w, b3.x,b3.y,b3.z,b3.w};
        float Cv[16] = {c0.x,c0.y,c0.z,c0.w, c1.x,c1.y,c1.z,c1.w,
                        c2.x,c2.y,c2.z,c2.w, c3.x,c3.y,c3.z,c3.w};
        float y = 0.f;
#pragma unroll
        for (int s = 0; s < 16; s++) {
            float a = __expf(dtv * A[s]);
            h[s] = fmaf(a, h[s], dx * Bv[s]);
            y = fmaf(h[s], Cv[s], y);
        }
        Tx[t][d] = fmaf(Dd, x, y);   // in-place: element owned by this thread only
    }
    __syncthreads();
#pragma unroll
    for (int jj = 0; jj < 8; jj++) {
        int lin = tid + jj * 256;
        int dd = lin >> 3, tq = (lin & 7) * 4;
        float4 sz = *(const float4*)&szt[(size_t)dd * NN + t0 + tq];
        float4 o;
        o.x = Tx[tq + 0][dd] * sz.x;
        o.y = Tx[tq + 1][dd] * sz.y;
        o.z = Tx[tq + 2][dd] * sz.z;
        o.w = Tx[tq + 3][dd] * sz.w;
        *(float4*)&yt[(size_t)dd * NN + t0 + tq] = o;
    }
}

// ---------------------------------------------------------------- output heads (ge_norm folded in)
__global__ void heads_kernel(const float* __restrict__ ge, const int* __restrict__ counts,
                             const float* Wc, const float* bc, const float* Wh, const float* bh,
                             const float* Wt, const float* bt, const float* Wp1, const float* bp1,
                             const float* Wp2, const float* bp2, const float* Wd, const float* bd,
                             const float* Ws, const float* bs, float* __restrict__ out) {
    int col = blockIdx.x * blockDim.x + threadIdx.x;
    int b = blockIdx.y;
    if (col >= OUTW) return;
    const float* W; const float* bi; int lc, w;
    if (col < 1)         { W = Wc;  bi = bc;  lc = col;        w = 1; }
    else if (col < 5)    { W = Wh;  bi = bh;  lc = col - 1;    w = 4; }
    else if (col < 8)    { W = Wt;  bi = bt;  lc = col - 5;    w = 3; }
    else if (col < 520)  { W = Wp1; bi = bp1; lc = col - 8;    w = 512; }
    else if (col < 1032) { W = Wp2; bi = bp2; lc = col - 520;  w = 512; }
    else if (col < 1544) { W = Wd;  bi = bd;  lc = col - 1032; w = 512; }
    else                 { W = Ws;  bi = bs;  lc = col - 1544; w = 8; }
    float scale = 1.f / fmaxf((float)counts[b], 1.f);
    float dot = 0.f;
#pragma unroll 8
    for (int f = 0; f < HH; f++) dot = fmaf(ge[b * HH + f], W[f * w + lc], dot);
    out[(size_t)b * OUTW + col] = bi[lc] + scale * dot;
}

// ---------------------------------------------------------------- launch
extern "C" void kernel_launch(void* const* d_in, const int* in_sizes, int n_in,
                              void* d_out, int out_size, void* d_ws, size_t ws_size,
                              hipStream_t stream) {
    const float* nf      = (const float*)d_in[0];
    const int*   ei      = (const int*)d_in[1];
    const int*   batch   = (const int*)d_in[2];
    const float* W_in    = (const float*)d_in[3];
    const float* b_in    = (const float*)d_in[4];
    const float* W_g1    = (const float*)d_in[5];
    const float* b_g1    = (const float*)d_in[6];
    const float* W_g2    = (const float*)d_in[7];
    const float* b_g2    = (const float*)d_in[8];
    const float* W_inproj= (const float*)d_in[9];
    const float* conv_w  = (const float*)d_in[10];
    const float* conv_b  = (const float*)d_in[11];
    const float* W_xproj = (const float*)d_in[12];
    const float* W_dt    = (const float*)d_in[13];
    const float* b_dt    = (const float*)d_in[14];
    const float* A_log   = (const float*)d_in[15];
    const float* D_p     = (const float*)d_in[16];
    const float* W_out   = (const float*)d_in[17];
    const float* gamma   = (const float*)d_in[18];
    const float* beta    = (const float*)d_in[19];
    const float* Wc = (const float*)d_in[20]; const float* bc = (const float*)d_in[21];
    const float* Wh = (const float*)d_in[22]; const float* bh = (const float*)d_in[23];
    const float* Wt = (const float*)d_in[24]; const float* bt = (const float*)d_in[25];
    const float* Wp1= (const float*)d_in[26]; const float* bp1= (const float*)d_in[27];
    const float* Wp2= (const float*)d_in[28]; const float* bp2= (const float*)d_in[29];
    const float* Wd = (const float*)d_in[30]; const float* bd = (const float*)d_in[31];
    const float* Ws = (const float*)d_in[32]; const float* bs = (const float*)d_in[33];

    const int* e_src = ei;
    const int* e_dst = ei + EE;

    // workspace layout (floats, then ints)
    float* w = (float*)d_ws;
    size_t o = 0;
    float* F0   = w + o; o += (size_t)NN * HH;   // dead during scan -> CHP
    float* F1   = w + o; o += (size_t)NN * HH;   // bf16 xw buffer lives here; dead during scan -> CHH
    float* F2   = w + o; o += (size_t)NN * HH;
    float* XZT  = w + o; o += (size_t)NN * 512;  // xz TRANSPOSED [512][NN]; dead after conv:
    float* YT   = XZT;                            //   y^T [DI][NN]
    float* XST  = w + o; o += (size_t)NN * DI;   // x (conv+silu), transposed [DI][NN]
    float* SZT  = w + o; o += (size_t)NN * DI;   // silu(z), transposed [DI][NN]
    float* DBLT = w + o; o += (size_t)NN * 40;   // [40][NN]
    float* GE   = w + o; o += BB * HH;
    float* DINV = w + o; o += NN;
    int* ip = (int*)(w + o);
    int* CNT    = ip; ip += NN;
    int* ROWPTR = ip; ip += NN + 1;
    int* CURSOR = ip; ip += NN;
    int* COL    = ip; ip += EE;
    int* COUNTS = ip; ip += BB;

    unsigned short* XW16 = (unsigned short*)F1;   // bf16 [NN][HH] (4MB, first half of F1)

    // overlays (regions dead during the scan)
    float* CHP  = F0;                         // NCH*4096 = 2M floats (== F0 exactly)
    float* CHH  = F1;                         // 2M floats
    float* INI  = CHP;                        // init written in-place over chkP (phase2)

    // zero scratch (single kernel instead of 3 memsets)
    zero_kernel<<<(NN + 255) / 256, 256, 0, stream>>>(CNT, GE, COUNTS);

    // CSR build
    deg_kernel<<<EE / 256, 256, 0, stream>>>(e_dst, CNT);
    prefix_kernel<<<1, 1024, 0, stream>>>(CNT, ROWPTR, CURSOR, DINV);
    scatter_kernel<<<EE / 256, 256, 0, stream>>>(e_src, e_dst, CURSOR, COL);

    // xw1 = relu(nf @ W_in + b_in) @ W_g1, stored bf16 (h0 never materialized)
    gemm_in_g1<<<dim3(2, NN / 64), 256, 0, stream>>>(nf, W_in, b_in, W_g1, XW16);
    gcn_gather4<<<NN / 8, 256, 0, stream>>>(XW16, ROWPTR, COL, DINV, b_g1, F0);
    // GCN layer 2: xw2 stored bf16
    gemm_k_bf16<<<dim3(2, NN / 64), 256, 0, stream>>>(F0, W_g2, XW16, NN, HH, HH);
    gcn_gather4<<<NN / 8, 256, 0, stream>>>(XW16, ROWPTR, COL, DINV, b_g2, F2);  // F2 = h_gnn

    // xz^T = (h_gnn @ W_inproj)^T  (transposed store: all consumers want [512][NN])
    gemm_big512_t<<<dim3(4, NN / 128), 512, 0, stream>>>(F2, W_inproj, XZT, NN, 512, HH);
    // conv + silu over contiguous rows -> XST; silu(z) -> SZT (pure streaming, no LDS)
    conv_silu_rows<<<dim3(NN / 1024, 512), 256, 0, stream>>>(XZT, conv_w, conv_b, XST, SZT);
    // dbl = xs @ W_xproj, written directly transposed -> DBLT (fused)
    gemm_at_dblt<<<NN / 64, 256, 0, stream>>>(XST, W_xproj, DBLT);

    // Mamba scan, shuffle-free: one d per thread, 16 states in registers, float4 staging
    scan_phase1<<<NCH, 256, 0, stream>>>(XST, DBLT, A_log, W_dt, b_dt, CHP, CHH);
    scan_phase2<<<16, 256, 0, stream>>>(CHP, CHH, INI);
    scan_phase3<<<NCH, 256, 0, stream>>>(XST, DBLT, A_log, W_dt, b_dt, INI, D_p, SZT, YT);

    // h_mamba = y @ W_out; + h_gnn; LayerNorm; pooled directly into GE (h_final never stored)
    gemm_at_ln_pool<<<NN / 32, 256, 0, stream>>>(YT, W_out, F2, gamma, beta, batch, GE, COUNTS);

    // heads (ge_norm folded in)
    heads_kernel<<<dim3((OUTW + 127) / 128, BB), 128, 0, stream>>>(
        GE, COUNTS, Wc, bc, Wh, bh, Wt, bt, Wp1, bp1, Wp2, bp2, Wd, bd, Ws, bs, (float*)d_out);
}